// Round 1
// baseline (1536.928 us; speedup 1.0000x reference)
//
#include <hip/hip_runtime.h>
#include <hip/hip_bf16.h>

typedef unsigned short u16;

constexpr int B_ = 16, C_ = 192, H_ = 56, W_ = 56;
constexpr int N_ = H_ * W_;   // 3136
constexpr int A_ = 768;       // attn_dim
constexpr int Dq = 192;       // d_qk
constexpr int Vd = 384;       // d_v
constexpr float EPSf = 1e-6f;

__device__ __forceinline__ float bits2f(u16 u) {
  return __uint_as_float(((unsigned)u) << 16);
}
__device__ __forceinline__ u16 f2bits(float f) {
  __hip_bfloat16 h = __float2bfloat16(f);
  u16 u;
  __builtin_memcpy(&u, &h, sizeof(u));
  return u;
}
__device__ __forceinline__ float silu_f(float v) { return v / (1.0f + __expf(-v)); }
__device__ __forceinline__ float sigm_f(float v) { return 1.0f / (1.0f + __expf(-v)); }

__device__ __forceinline__ void fma_4x4(const float a[4], const float b[4], float acc[4][4]) {
#pragma unroll
  for (int i = 0; i < 4; ++i)
#pragma unroll
    for (int j = 0; j < 4; ++j) acc[i][j] = fmaf(a[i], b[j], acc[i][j]);
}

// ---------------- K1: proj GEMM  y0[b,o,n] = sum_c x[b,c,n]*pw[o,c] + pb[o]
__global__ __launch_bounds__(256) void k_proj(const float* __restrict__ x,
                                              const float* __restrict__ pw,
                                              const float* __restrict__ pb,
                                              u16* __restrict__ y0) {
  const int n0 = blockIdx.x * 64;
  const int o0 = blockIdx.y * 64;
  const int b = blockIdx.z;
  __shared__ float As[16][64];  // [k][o]
  __shared__ float Bs[16][64];  // [k][n]
  const int tid = threadIdx.x;
  const int tx = tid & 15, ty = tid >> 4;
  float acc[4][4] = {};
  for (int k0 = 0; k0 < C_; k0 += 16) {
    {
      const int li = tid >> 4, lk = tid & 15;
#pragma unroll
      for (int r = 0; r < 4; ++r)
        As[lk][li + 16 * r] = pw[(size_t)(o0 + li + 16 * r) * C_ + k0 + lk];
    }
    {
      const int lk = tid >> 6, lj = tid & 63;
#pragma unroll
      for (int r = 0; r < 4; ++r)
        Bs[lk + 4 * r][lj] = x[((size_t)b * C_ + k0 + lk + 4 * r) * N_ + n0 + lj];
    }
    __syncthreads();
#pragma unroll
    for (int kk = 0; kk < 16; ++kk) {
      float a[4], bb[4];
      *(float4*)a = *(const float4*)&As[kk][ty * 4];
      *(float4*)bb = *(const float4*)&Bs[kk][tx * 4];
      fma_4x4(a, bb, acc);
    }
    __syncthreads();
  }
#pragma unroll
  for (int i = 0; i < 4; ++i) {
    const float bias = pb[o0 + ty * 4 + i];
    ushort4 pk;
    pk.x = f2bits(acc[i][0] + bias);
    pk.y = f2bits(acc[i][1] + bias);
    pk.z = f2bits(acc[i][2] + bias);
    pk.w = f2bits(acc[i][3] + bias);
    *(ushort4*)&y0[((size_t)b * A_ + o0 + ty * 4 + i) * N_ + n0 + tx * 4] = pk;
  }
}

// ---------------- K2: depthwise 3x3 + bias + residual
__global__ __launch_bounds__(256) void k_dwc(const u16* __restrict__ y0,
                                             const float* __restrict__ cw,
                                             const float* __restrict__ cb,
                                             u16* __restrict__ y) {
  const int ba = blockIdx.x;  // b*A_ + a
  const int a = ba % A_;
  __shared__ float t[58 * 58];
  const u16* p = y0 + (size_t)ba * N_;
  for (int idx = threadIdx.x; idx < 58 * 58; idx += 256) {
    const int hh = idx / 58 - 1, ww = idx % 58 - 1;
    float v = 0.f;
    if ((unsigned)hh < 56u && (unsigned)ww < 56u) v = bits2f(p[hh * 56 + ww]);
    t[idx] = v;
  }
  __syncthreads();
  float w[9];
#pragma unroll
  for (int i = 0; i < 9; ++i) w[i] = cw[a * 9 + i];
  const float bias = cb[a];
  u16* q = y + (size_t)ba * N_;
  for (int idx = threadIdx.x; idx < N_; idx += 256) {
    const int hh = idx / 56, ww = idx % 56;
    const float* tp = &t[hh * 58 + ww];
    float s = bias + tp[59];  // bias + residual center
    s = fmaf(w[0], tp[0], s);
    s = fmaf(w[1], tp[1], s);
    s = fmaf(w[2], tp[2], s);
    s = fmaf(w[3], tp[58], s);
    s = fmaf(w[4], tp[59], s);
    s = fmaf(w[5], tp[60], s);
    s = fmaf(w[6], tp[116], s);
    s = fmaf(w[7], tp[117], s);
    s = fmaf(w[8], tp[118], s);
    q[idx] = f2bits(s);
  }
}

// ---------------- K3: kfmean[b,d] = mean_n silu(k[b,d,n])
__global__ __launch_bounds__(256) void k_kfmean(const u16* __restrict__ y,
                                                float* __restrict__ kfmean) {
  const int bd = blockIdx.x;
  const int b = bd / Dq, d = bd % Dq;
  const u16* p = y + ((size_t)b * A_ + Dq + d) * N_;
  float s = 0.f;
  for (int i = threadIdx.x; i < N_; i += 256) s += silu_f(bits2f(p[i]));
  __shared__ float r[256];
  r[threadIdx.x] = s;
  __syncthreads();
  for (int st = 128; st > 0; st >>= 1) {
    if (threadIdx.x < st) r[threadIdx.x] += r[threadIdx.x + st];
    __syncthreads();
  }
  if (threadIdx.x == 0) kfmean[bd] = r[0] * (1.0f / (float)N_);
}

// ---------------- K4: vk[b,v,d] = (1/N) sum_n v[b,v,n]*silu(k[b,d,n])
__global__ __launch_bounds__(256) void k_vk(const u16* __restrict__ y,
                                            float* __restrict__ vkp) {
  const int d0 = blockIdx.x * 64;
  const int v0 = blockIdx.y * 64;
  const int b = blockIdx.z;
  __shared__ float vs[64][33];
  __shared__ float ks[64][33];
  const int tid = threadIdx.x;
  const int tx = tid & 15, ty = tid >> 4;
  const u16* vbase = y + ((size_t)b * A_ + 2 * Dq) * N_;
  const u16* kbase = y + ((size_t)b * A_ + Dq) * N_;
  float acc[4][4] = {};
  const int lrow = tid >> 3;       // 0..31
  const int lcol = (tid & 7) * 4;  // 0..28
  for (int n0 = 0; n0 < N_; n0 += 32) {
#pragma unroll
    for (int r = 0; r < 2; ++r) {
      const int row = lrow + 32 * r;
      const ushort4 uv = *(const ushort4*)&vbase[(size_t)(v0 + row) * N_ + n0 + lcol];
      vs[row][lcol + 0] = bits2f(uv.x);
      vs[row][lcol + 1] = bits2f(uv.y);
      vs[row][lcol + 2] = bits2f(uv.z);
      vs[row][lcol + 3] = bits2f(uv.w);
      const ushort4 uk = *(const ushort4*)&kbase[(size_t)(d0 + row) * N_ + n0 + lcol];
      ks[row][lcol + 0] = silu_f(bits2f(uk.x));
      ks[row][lcol + 1] = silu_f(bits2f(uk.y));
      ks[row][lcol + 2] = silu_f(bits2f(uk.z));
      ks[row][lcol + 3] = silu_f(bits2f(uk.w));
    }
    __syncthreads();
#pragma unroll
    for (int kk = 0; kk < 32; ++kk) {
      float a[4], bb[4];
#pragma unroll
      for (int i = 0; i < 4; ++i) a[i] = vs[ty * 4 + i][kk];
#pragma unroll
      for (int j = 0; j < 4; ++j) bb[j] = ks[tx * 4 + j][kk];
      fma_4x4(a, bb, acc);
    }
    __syncthreads();
  }
  const float sc = 1.0f / (float)N_;
#pragma unroll
  for (int i = 0; i < 4; ++i)
#pragma unroll
    for (int j = 0; j < 4; ++j)
      vkp[((size_t)b * Vd + v0 + ty * 4 + i) * Dq + d0 + tx * 4 + j] = acc[i][j] * sc;
}

// ---------------- K5a: attnraw = (vk@qf / z) * sigmoid(g_w@xs + g_b)
__global__ __launch_bounds__(256) void k_gateattn(const u16* __restrict__ y,
                                                  const float* __restrict__ kfmean,
                                                  const float* __restrict__ vkp,
                                                  const float* __restrict__ gw,
                                                  const float* __restrict__ gb,
                                                  u16* __restrict__ attnraw) {
  const int n0 = blockIdx.x * 64;
  const int v0 = blockIdx.y * 64;
  const int b = blockIdx.z;
  const int tid = threadIdx.x;
  const int tx = tid & 15, ty = tid >> 4;
  __shared__ u16 qf_s[Dq][64];
  __shared__ float wk_s[16][64];
  __shared__ u16 xs_s[16][64];
  __shared__ float kfm_s[Dq];
  __shared__ float zinv_s[64];
  const u16* ybase = y + (size_t)b * A_ * N_;
  // stage qf = silu(q) as bf16 into LDS
  {
    const int jv = (tid & 15) * 4;
#pragma unroll
    for (int r = 0; r < 12; ++r) {
      const int d = (tid >> 4) + 16 * r;
      const ushort4 u = *(const ushort4*)&ybase[(size_t)d * N_ + n0 + jv];
      ushort4 o;
      o.x = f2bits(silu_f(bits2f(u.x)));
      o.y = f2bits(silu_f(bits2f(u.y)));
      o.z = f2bits(silu_f(bits2f(u.z)));
      o.w = f2bits(silu_f(bits2f(u.w)));
      *(ushort4*)&qf_s[d][jv] = o;
    }
  }
  for (int i = tid; i < Dq; i += 256) kfm_s[i] = kfmean[b * Dq + i];
  __syncthreads();
  if (tid < 64) {
    float z = 0.f;
    for (int d = 0; d < Dq; ++d) z = fmaf(kfm_s[d], bits2f(qf_s[d][tid]), z);
    zinv_s[tid] = 1.0f / (z + EPSf);
  }
  __syncthreads();
  // attn0 = vk @ qf   (K = 192)
  float acc[4][4] = {};
  for (int k0 = 0; k0 < Dq; k0 += 16) {
    {
      const int li = tid >> 4, lk = tid & 15;
#pragma unroll
      for (int r = 0; r < 4; ++r)
        wk_s[lk][li + 16 * r] = vkp[((size_t)b * Vd + v0 + li + 16 * r) * Dq + k0 + lk];
    }
    __syncthreads();
#pragma unroll
    for (int kk = 0; kk < 16; ++kk) {
      float a[4], bb[4];
      *(float4*)a = *(const float4*)&wk_s[kk][ty * 4];
      const ushort4 u = *(const ushort4*)&qf_s[k0 + kk][tx * 4];
      bb[0] = bits2f(u.x);
      bb[1] = bits2f(u.y);
      bb[2] = bits2f(u.z);
      bb[3] = bits2f(u.w);
      fma_4x4(a, bb, acc);
    }
    __syncthreads();
  }
  // gate pre-activation = g_w @ xs   (K = 768)
  float gcc[4][4] = {};
  for (int c0 = 0; c0 < A_; c0 += 16) {
    {
      const int li = tid >> 4, lk = tid & 15;
#pragma unroll
      for (int r = 0; r < 4; ++r)
        wk_s[lk][li + 16 * r] = gw[(size_t)(v0 + li + 16 * r) * A_ + c0 + lk];
    }
    {
      const int kk = tid >> 4, jv = (tid & 15) * 4;
      *(ushort4*)&xs_s[kk][jv] = *(const ushort4*)&ybase[(size_t)(c0 + kk) * N_ + n0 + jv];
    }
    __syncthreads();
#pragma unroll
    for (int kk = 0; kk < 16; ++kk) {
      float a[4], bb[4];
      *(float4*)a = *(const float4*)&wk_s[kk][ty * 4];
      const ushort4 u = *(const ushort4*)&xs_s[kk][tx * 4];
      bb[0] = bits2f(u.x);
      bb[1] = bits2f(u.y);
      bb[2] = bits2f(u.z);
      bb[3] = bits2f(u.w);
      fma_4x4(a, bb, gcc);
    }
    __syncthreads();
  }
  // combine + write
#pragma unroll
  for (int i = 0; i < 4; ++i) {
    const float gbv = gb[v0 + ty * 4 + i];
    ushort4 pk;
    float vv[4];
#pragma unroll
    for (int j = 0; j < 4; ++j) {
      const float gate = sigm_f(gcc[i][j] + gbv);
      vv[j] = acc[i][j] * zinv_s[tx * 4 + j] * gate;
    }
    pk.x = f2bits(vv[0]);
    pk.y = f2bits(vv[1]);
    pk.z = f2bits(vv[2]);
    pk.w = f2bits(vv[3]);
    *(ushort4*)&attnraw[((size_t)b * Vd + v0 + ty * 4 + i) * N_ + n0 + tx * 4] = pk;
  }
}

// ---------------- K5b: per-column rms over 384, final combine (in-place)
__global__ __launch_bounds__(256) void k_rmsfinal(const u16* __restrict__ y,
                                                  const float* __restrict__ anw,
                                                  const float* __restrict__ svw,
                                                  u16* __restrict__ attn) {
  const int n0 = blockIdx.x * 64;
  const int b = blockIdx.y;
  const int tid = threadIdx.x;
  __shared__ float red_s[4][64];
  __shared__ float rinv_s[64];
  u16* abase = attn + (size_t)b * Vd * N_;
  {
    const int j = tid & 63, g = tid >> 6;
    float ss = 0.f;
    for (int vv = g; vv < Vd; vv += 4) {
      const float t = bits2f(abase[(size_t)vv * N_ + n0 + j]);
      ss = fmaf(t, t, ss);
    }
    red_s[g][j] = ss;
  }
  __syncthreads();
  if (tid < 64) {
    const float m =
        (red_s[0][tid] + red_s[1][tid] + red_s[2][tid] + red_s[3][tid]) * (1.0f / (float)Vd);
    rinv_s[tid] = rsqrtf(m + EPSf);
  }
  __syncthreads();
  const u16* vbase = y + ((size_t)b * A_ + 2 * Dq) * N_;
  for (int idx = tid; idx < Vd * 64; idx += 256) {
    const int vv = idx >> 6, jj = idx & 63;
    const float val = bits2f(abase[(size_t)vv * N_ + n0 + jj]) * rinv_s[jj] * anw[vv] +
                      bits2f(vbase[(size_t)vv * N_ + n0 + jj]) * svw[vv];
    abase[(size_t)vv * N_ + n0 + jj] = f2bits(val);
  }
}

// ---------------- K6: out GEMM  out[b,c,n] = sum_v ow[c,v]*attn[b,v,n] + ob[c]
__global__ __launch_bounds__(256) void k_out(const u16* __restrict__ attn,
                                             const float* __restrict__ ow,
                                             const float* __restrict__ ob,
                                             float* __restrict__ out) {
  const int n0 = blockIdx.x * 64;
  const int c0 = blockIdx.y * 64;
  const int b = blockIdx.z;
  __shared__ float As[16][64];
  __shared__ u16 Bs[16][64];
  const int tid = threadIdx.x;
  const int tx = tid & 15, ty = tid >> 4;
  float acc[4][4] = {};
  for (int k0 = 0; k0 < Vd; k0 += 16) {
    {
      const int li = tid >> 4, lk = tid & 15;
#pragma unroll
      for (int r = 0; r < 4; ++r)
        As[lk][li + 16 * r] = ow[(size_t)(c0 + li + 16 * r) * Vd + k0 + lk];
    }
    {
      const int kk = tid >> 4, jv = (tid & 15) * 4;
      *(ushort4*)&Bs[kk][jv] = *(const ushort4*)&attn[((size_t)b * Vd + k0 + kk) * N_ + n0 + jv];
    }
    __syncthreads();
#pragma unroll
    for (int kk = 0; kk < 16; ++kk) {
      float a[4], bb[4];
      *(float4*)a = *(const float4*)&As[kk][ty * 4];
      const ushort4 u = *(const ushort4*)&Bs[kk][tx * 4];
      bb[0] = bits2f(u.x);
      bb[1] = bits2f(u.y);
      bb[2] = bits2f(u.z);
      bb[3] = bits2f(u.w);
      fma_4x4(a, bb, acc);
    }
    __syncthreads();
  }
#pragma unroll
  for (int i = 0; i < 4; ++i) {
    const float bias = ob[c0 + ty * 4 + i];
    float4 o;
    o.x = acc[i][0] + bias;
    o.y = acc[i][1] + bias;
    o.z = acc[i][2] + bias;
    o.w = acc[i][3] + bias;
    *(float4*)&out[((size_t)b * C_ + c0 + ty * 4 + i) * N_ + n0 + tx * 4] = o;
  }
}

extern "C" void kernel_launch(void* const* d_in, const int* in_sizes, int n_in,
                              void* d_out, int out_size, void* d_ws, size_t ws_size,
                              hipStream_t stream) {
  (void)in_sizes; (void)n_in; (void)out_size; (void)ws_size;
  const float* x = (const float*)d_in[0];
  const float* pw = (const float*)d_in[1];
  const float* pb = (const float*)d_in[2];
  const float* cw = (const float*)d_in[3];
  const float* cb = (const float*)d_in[4];
  const float* gw = (const float*)d_in[5];
  const float* gb = (const float*)d_in[6];
  const float* anw = (const float*)d_in[7];
  const float* svw = (const float*)d_in[8];
  const float* ow = (const float*)d_in[9];
  const float* ob = (const float*)d_in[10];
  float* out = (float*)d_out;

  char* ws = (char*)d_ws;
  const size_t szY = (size_t)B_ * A_ * N_ * 2;  // 77,070,336 bytes
  u16* y0 = (u16*)(ws);                         // [B, A, N] bf16
  u16* y = (u16*)(ws + szY);                    // [B, A, N] bf16
  float* kfm = (float*)(ws + 2 * szY);          // [B, Dq]
  float* vkp = (float*)(ws + 2 * szY + 16384);  // [B, Vd, Dq]
  u16* attn = (u16*)(ws);                       // [B, Vd, N] bf16 (aliases y0, dead by then)

  k_proj<<<dim3(49, 12, 16), 256, 0, stream>>>(x, pw, pb, y0);
  k_dwc<<<dim3(B_ * A_), 256, 0, stream>>>(y0, cw, cb, y);
  k_kfmean<<<dim3(B_ * Dq), 256, 0, stream>>>(y, kfm);
  k_vk<<<dim3(3, 6, 16), 256, 0, stream>>>(y, vkp);
  k_gateattn<<<dim3(49, 6, 16), 256, 0, stream>>>(y, kfm, vkp, gw, gb, attn);
  k_rmsfinal<<<dim3(49, 16), 256, 0, stream>>>(y, anw, svw, attn);
  k_out<<<dim3(49, 3, 16), 256, 0, stream>>>(attn, ow, ob, out);
}

// Round 2
// 433.347 us; speedup vs baseline: 3.5466x; 3.5466x over previous
//
#include <hip/hip_runtime.h>
#include <hip/hip_bf16.h>

typedef unsigned short u16;
typedef __attribute__((ext_vector_type(8))) short bf16x8;
typedef __attribute__((ext_vector_type(4))) float f32x4;

constexpr int B_ = 16, C_ = 192, H_ = 56, W_ = 56;
constexpr int N_ = H_ * W_;   // 3136
constexpr int A_ = 768;       // attn_dim
constexpr int Dq = 192;       // d_qk
constexpr int Vd = 384;       // d_v
constexpr float EPSf = 1e-6f;

union U8 { bf16x8 v; u16 s[8]; unsigned u[4]; };

__device__ __forceinline__ float bits2f(u16 u) {
  return __uint_as_float(((unsigned)u) << 16);
}
__device__ __forceinline__ u16 f2bits(float f) {
  __hip_bfloat16 h = __float2bfloat16(f);
  u16 u;
  __builtin_memcpy(&u, &h, sizeof(u));
  return u;
}
__device__ __forceinline__ float silu_f(float v) { return v / (1.0f + __expf(-v)); }
__device__ __forceinline__ float sigm_f(float v) { return 1.0f / (1.0f + __expf(-v)); }

__device__ __forceinline__ f32x4 MFMA(bf16x8 a, bf16x8 b, f32x4 c) {
  return __builtin_amdgcn_mfma_f32_16x16x32_bf16(a, b, c, 0, 0, 0);
}

// ============ K1: proj GEMM  y0t[b][n][o] = sum_c pw[o,c]*x[b,c,n] + pb[o]
// persistent over 12 o-blocks; Xt staged once (full K=192).
__global__ __launch_bounds__(256, 3) void k_proj(const float* __restrict__ x,
                                                 const float* __restrict__ pw,
                                                 const float* __restrict__ pb,
                                                 u16* __restrict__ y0t) {
  const int n0 = blockIdx.x * 64;
  const int b = blockIdx.y;
  __shared__ u16 Xt[64][200];  // [n][c], stride 400B (16B mult)
  __shared__ u16 Wa[64][200];  // [o][c]
  const int t = threadIdx.x;
  const int lane = t & 63, wid = t >> 6, wm = wid >> 1, wn = wid & 1;
  const int fr = lane & 15, fg = lane >> 4;

  // stage Xt: x[b][c][n] -> Xt[n][c] (transpose via n-pair float2 reads)
  {
    const int p = t & 31, co = t >> 5;  // n-pair 0..31, c-octet 0..7
    const float* xb = x + (size_t)b * C_ * N_ + n0 + 2 * p;
#pragma unroll
    for (int rnd = 0; rnd < 3; ++rnd) {
      const int c0 = rnd * 64 + co * 8;
      float2 v[8];
#pragma unroll
      for (int i = 0; i < 8; ++i) v[i] = *(const float2*)&xb[(size_t)(c0 + i) * N_];
      U8 r0, r1;
#pragma unroll
      for (int i = 0; i < 8; ++i) { r0.s[i] = f2bits(v[i].x); r1.s[i] = f2bits(v[i].y); }
      *(bf16x8*)&Xt[2 * p][c0] = r0.v;
      *(bf16x8*)&Xt[2 * p + 1][c0] = r1.v;
    }
  }

  f32x4 acc[2][2];
  for (int ob = 0; ob < 12; ++ob) {
    // stage Wa: pw rows (f32 row-major, c contiguous)
    {
      const int o = t >> 2, cs = t & 3;
      const float* pwr = pw + (size_t)(ob * 64 + o) * C_ + cs * 8;
#pragma unroll
      for (int rc = 0; rc < 6; ++rc) {
        float4 v0 = *(const float4*)&pwr[rc * 32];
        float4 v1 = *(const float4*)&pwr[rc * 32 + 4];
        U8 r;
        r.s[0] = f2bits(v0.x); r.s[1] = f2bits(v0.y); r.s[2] = f2bits(v0.z); r.s[3] = f2bits(v0.w);
        r.s[4] = f2bits(v1.x); r.s[5] = f2bits(v1.y); r.s[6] = f2bits(v1.z); r.s[7] = f2bits(v1.w);
        *(bf16x8*)&Wa[o][rc * 32 + cs * 8] = r.v;
      }
    }
    __syncthreads();
#pragma unroll
    for (int mi = 0; mi < 2; ++mi)
#pragma unroll
      for (int ni = 0; ni < 2; ++ni) acc[mi][ni] = (f32x4){0.f, 0.f, 0.f, 0.f};
#pragma unroll
    for (int ks = 0; ks < 6; ++ks) {
      bf16x8 a0 = *(const bf16x8*)&Wa[wm * 32 + fr][ks * 32 + fg * 8];
      bf16x8 a1 = *(const bf16x8*)&Wa[wm * 32 + 16 + fr][ks * 32 + fg * 8];
      bf16x8 b0 = *(const bf16x8*)&Xt[wn * 32 + fr][ks * 32 + fg * 8];
      bf16x8 b1 = *(const bf16x8*)&Xt[wn * 32 + 16 + fr][ks * 32 + fg * 8];
      acc[0][0] = MFMA(a0, b0, acc[0][0]);
      acc[0][1] = MFMA(a0, b1, acc[0][1]);
      acc[1][0] = MFMA(a1, b0, acc[1][0]);
      acc[1][1] = MFMA(a1, b1, acc[1][1]);
    }
#pragma unroll
    for (int mi = 0; mi < 2; ++mi) {
      const int obase = ob * 64 + wm * 32 + mi * 16 + fg * 4;
      const float pb0 = pb[obase], pb1 = pb[obase + 1], pb2 = pb[obase + 2], pb3 = pb[obase + 3];
#pragma unroll
      for (int ni = 0; ni < 2; ++ni) {
        const int n = n0 + wn * 32 + ni * 16 + fr;
        ushort4 pk;
        pk.x = f2bits(acc[mi][ni][0] + pb0);
        pk.y = f2bits(acc[mi][ni][1] + pb1);
        pk.z = f2bits(acc[mi][ni][2] + pb2);
        pk.w = f2bits(acc[mi][ni][3] + pb3);
        *(ushort4*)&y0t[((size_t)b * N_ + n) * A_ + obase] = pk;
      }
    }
    __syncthreads();  // before Wa overwrite
  }
}

// ============ K2: depthwise 3x3 + bias + residual.  y0t[b][n][a] -> yt[b][n][a]
__global__ __launch_bounds__(256) void k_dwc(const u16* __restrict__ y0t,
                                             const float* __restrict__ cw,
                                             const float* __restrict__ cb,
                                             u16* __restrict__ yt) {
  const int pid = blockIdx.x;
  const int L = (pid & 7) * 336 + (pid >> 3);  // chunked XCD swizzle (2688 = 8*336)
  const int h = L % 56, at = (L / 56) % 3, b = L / 168;
  const int t = threadIdx.x;
  const int a = at * 256 + (t & 31) * 8;
  const int wl = t >> 5;
  float w9[9][8];
  float bias[8];
#pragma unroll
  for (int j = 0; j < 8; ++j) {
    bias[j] = cb[a + j];
#pragma unroll
    for (int k = 0; k < 9; ++k) w9[k][j] = cw[(a + j) * 9 + k];
  }
  const u16* src = y0t + (size_t)b * N_ * A_ + a;
  u16* dst = yt + (size_t)b * N_ * A_ + a;
  const bool hok0 = h > 0, hok2 = h < 55;
  for (int wc = 0; wc < 7; ++wc) {
    const int w = wc * 8 + wl;
    const bool wok0 = w > 0, wok2 = w < 55;
    U8 nb[9];
#pragma unroll
    for (int dh = -1; dh <= 1; ++dh) {
      const bool hok = (dh == -1) ? hok0 : ((dh == 1) ? hok2 : true);
#pragma unroll
      for (int dw = -1; dw <= 1; ++dw) {
        const int k = (dh + 1) * 3 + (dw + 1);
        const bool ok = hok && ((dw == -1) ? wok0 : ((dw == 1) ? wok2 : true));
        if (ok)
          nb[k].v = *(const bf16x8*)&src[(size_t)((h + dh) * 56 + (w + dw)) * A_];
        else
          nb[k].u[0] = nb[k].u[1] = nb[k].u[2] = nb[k].u[3] = 0u;
      }
    }
    U8 o;
#pragma unroll
    for (int j = 0; j < 8; ++j) {
      float s = bias[j] + bits2f(nb[4].s[j]);  // bias + residual(center)
#pragma unroll
      for (int k = 0; k < 9; ++k) s = fmaf(w9[k][j], bits2f(nb[k].s[j]), s);
      o.s[j] = f2bits(s);
    }
    *(bf16x8*)&dst[(size_t)(h * 56 + w) * A_] = o.v;
  }
}

// ============ K3: kfmean partials. kfp[ns][b][d] = (1/N) sum_{n in chunk} silu(k[d,n])
__global__ __launch_bounds__(256) void k_kfmean(const u16* __restrict__ yt,
                                                float* __restrict__ kfp) {
  const int ns = blockIdx.x, dc = blockIdx.y, b = blockIdx.z;
  const int t = threadIdx.x;
  const int dq = t & 15, nw = t >> 4;
  const u16* p = yt + ((size_t)b * N_ + ns * 448 + nw) * A_ + Dq + dc * 64 + dq * 4;
  float s0 = 0, s1 = 0, s2 = 0, s3 = 0;
#pragma unroll 4
  for (int i = 0; i < 28; ++i) {
    ushort4 u = *(const ushort4*)&p[(size_t)i * 16 * A_];
    s0 += silu_f(bits2f(u.x));
    s1 += silu_f(bits2f(u.y));
    s2 += silu_f(bits2f(u.z));
    s3 += silu_f(bits2f(u.w));
  }
  __shared__ float red[16][65];
  red[nw][dq * 4 + 0] = s0;
  red[nw][dq * 4 + 1] = s1;
  red[nw][dq * 4 + 2] = s2;
  red[nw][dq * 4 + 3] = s3;
  __syncthreads();
  if (t < 64) {
    float s = 0;
#pragma unroll
    for (int i = 0; i < 16; ++i) s += red[i][t];
    kfp[((size_t)ns * B_ + b) * Dq + dc * 64 + t] = s * (1.0f / (float)N_);
  }
}

// ============ K4: zinv[b][n] = 1/(sum_d kfm[d]*silu(q[d,n]) + EPS)
__global__ __launch_bounds__(256) void k_z(const u16* __restrict__ yt,
                                           const float* __restrict__ kfp,
                                           float* __restrict__ zinv) {
  const int b = blockIdx.y;
  const int n = blockIdx.x * 256 + threadIdx.x;
  __shared__ float kf[192];
  if (threadIdx.x < 192) {
    float s = 0;
#pragma unroll
    for (int ns = 0; ns < 7; ++ns) s += kfp[((size_t)ns * B_ + b) * Dq + threadIdx.x];
    kf[threadIdx.x] = s;
  }
  __syncthreads();
  if (n < N_) {
    const u16* p = yt + ((size_t)b * N_ + n) * A_;
    float z = 0;
#pragma unroll
    for (int j = 0; j < 24; ++j) {
      U8 u;
      u.v = *(const bf16x8*)&p[j * 8];
#pragma unroll
      for (int i = 0; i < 8; ++i) z = fmaf(kf[j * 8 + i], silu_f(bits2f(u.s[i])), z);
    }
    zinv[(size_t)b * N_ + n] = 1.0f / (z + EPSf);
  }
}

// ============ K5: vk GEMM. vkp[b][v][d] = (1/N) sum_n v[v,n]*silu(k[d,n])   (K = n)
__global__ __launch_bounds__(256) void k_vk(const u16* __restrict__ yt,
                                            float* __restrict__ vkp) {
  const int pid = blockIdx.x;
  const int L = (pid & 7) * 36 + (pid >> 3);  // 288 = 8*36
  const int dblk = L % 3, vblk = (L / 3) % 6, b = L / 18;
  const int t = threadIdx.x;
  const int lane = t & 63, wid = t >> 6, wm = wid >> 1, wn = wid & 1;
  const int fr = lane & 15, fg = lane >> 4;
  __shared__ u16 Va[64][72];  // [v][n] stride 144B
  __shared__ u16 Ka[64][72];  // [d][n]
  const int half = t >> 7;        // 0: stage V, 1: stage K(silu)
  const int ao = (t >> 4) & 7;    // a-octet
  const int p0 = t & 15;          // n-pair base
  const int abase = half ? (Dq + dblk * 64) : (2 * Dq + vblk * 64);
  const u16* sp = yt + (size_t)b * N_ * A_ + abase + ao * 8;

  f32x4 acc[2][2];
#pragma unroll
  for (int mi = 0; mi < 2; ++mi)
#pragma unroll
    for (int ni = 0; ni < 2; ++ni) acc[mi][ni] = (f32x4){0.f, 0.f, 0.f, 0.f};

  for (int n0 = 0; n0 < N_; n0 += 64) {
#pragma unroll
    for (int rr = 0; rr < 2; ++rr) {
      const int p = p0 + rr * 16;  // 0..31
      const int n = n0 + 2 * p;
      U8 r0, r1;
      r0.v = *(const bf16x8*)&sp[(size_t)n * A_];
      r1.v = *(const bf16x8*)&sp[(size_t)(n + 1) * A_];
      if (half) {
#pragma unroll
        for (int i = 0; i < 8; ++i) {
          r0.s[i] = f2bits(silu_f(bits2f(r0.s[i])));
          r1.s[i] = f2bits(silu_f(bits2f(r1.s[i])));
        }
      }
      u16(*Tile)[72] = half ? Ka : Va;
#pragma unroll
      for (int i = 0; i < 8; ++i) {
        unsigned pk = (unsigned)r0.s[i] & 0xffffu;
        pk |= ((unsigned)r1.s[i] & 0xffffu) << 16;
        *(unsigned*)&Tile[ao * 8 + i][2 * p] = pk;
      }
    }
    __syncthreads();
#pragma unroll
    for (int kf2 = 0; kf2 < 2; ++kf2) {
      bf16x8 a0 = *(const bf16x8*)&Va[wm * 32 + fr][kf2 * 32 + fg * 8];
      bf16x8 a1 = *(const bf16x8*)&Va[wm * 32 + 16 + fr][kf2 * 32 + fg * 8];
      bf16x8 b0 = *(const bf16x8*)&Ka[wn * 32 + fr][kf2 * 32 + fg * 8];
      bf16x8 b1 = *(const bf16x8*)&Ka[wn * 32 + 16 + fr][kf2 * 32 + fg * 8];
      acc[0][0] = MFMA(a0, b0, acc[0][0]);
      acc[0][1] = MFMA(a0, b1, acc[0][1]);
      acc[1][0] = MFMA(a1, b0, acc[1][0]);
      acc[1][1] = MFMA(a1, b1, acc[1][1]);
    }
    __syncthreads();
  }
  const float sc = 1.0f / (float)N_;
#pragma unroll
  for (int mi = 0; mi < 2; ++mi)
#pragma unroll
    for (int ni = 0; ni < 2; ++ni) {
      const int v = vblk * 64 + wm * 32 + mi * 16 + fg * 4;
      const int d = dblk * 64 + wn * 32 + ni * 16 + fr;
      float* o = vkp + ((size_t)b * Vd + v) * Dq + d;
      o[0 * Dq] = acc[mi][ni][0] * sc;
      o[1 * Dq] = acc[mi][ni][1] * sc;
      o[2 * Dq] = acc[mi][ni][2] * sc;
      o[3 * Dq] = acc[mi][ni][3] * sc;
    }
}

// ============ K6: fused attn0 (vk@qf /z) and gate (sigmoid(gw@xs+gb)); writes attnt[n][v]
__global__ __launch_bounds__(256, 3) void k_gateattn(const u16* __restrict__ yt,
                                                     const float* __restrict__ zinv,
                                                     const float* __restrict__ vkp,
                                                     const float* __restrict__ gw,
                                                     const float* __restrict__ gb,
                                                     u16* __restrict__ attnt) {
  const int pid = blockIdx.x;
  const int L = (pid & 7) * 196 + (pid >> 3);  // 1568 = 8*196
  const int vh = L & 1;
  const int n0 = ((L >> 1) % 49) * 64;
  const int b = L / 98;
  const int t = threadIdx.x;
  const int lane = t & 63, wid = t >> 6, wm = wid >> 1, wn = wid & 1;
  const int fr = lane & 15, fg = lane >> 4;
  __shared__ u16 Wa[192][40];
  __shared__ u16 Xt[64][40];
  __shared__ float zl[64];
  if (t < 64) zl[t] = zinv[(size_t)b * N_ + n0 + t];
  const u16* yb = yt + ((size_t)b * N_ + n0) * A_;

  f32x4 acc[6][2];
#pragma unroll
  for (int mi = 0; mi < 6; ++mi)
#pragma unroll
    for (int ni = 0; ni < 2; ++ni) acc[mi][ni] = (f32x4){0.f, 0.f, 0.f, 0.f};

  // ---- attn0 = vk @ qf, K = 192
  for (int ks = 0; ks < 6; ++ks) {
    {
      const int o = t >> 2, cs = t & 3;
#pragma unroll
      for (int rr = 0; rr < 3; ++rr) {
        const int v = rr * 64 + o;
        const float* src = vkp + ((size_t)b * Vd + vh * 192 + v) * Dq + ks * 32 + cs * 8;
        float4 v0 = *(const float4*)src;
        float4 v1 = *(const float4*)(src + 4);
        U8 r;
        r.s[0] = f2bits(v0.x); r.s[1] = f2bits(v0.y); r.s[2] = f2bits(v0.z); r.s[3] = f2bits(v0.w);
        r.s[4] = f2bits(v1.x); r.s[5] = f2bits(v1.y); r.s[6] = f2bits(v1.z); r.s[7] = f2bits(v1.w);
        *(bf16x8*)&Wa[v][cs * 8] = r.v;
      }
    }
    {
      const int n = t >> 2, aq = t & 3;
      U8 r;
      r.v = *(const bf16x8*)&yb[(size_t)n * A_ + ks * 32 + aq * 8];
#pragma unroll
      for (int i = 0; i < 8; ++i) r.s[i] = f2bits(silu_f(bits2f(r.s[i])));
      *(bf16x8*)&Xt[n][aq * 8] = r.v;
    }
    __syncthreads();
    bf16x8 bfr[2];
#pragma unroll
    for (int ni = 0; ni < 2; ++ni) bfr[ni] = *(const bf16x8*)&Xt[wn * 32 + ni * 16 + fr][fg * 8];
#pragma unroll
    for (int mi = 0; mi < 6; ++mi) {
      bf16x8 a = *(const bf16x8*)&Wa[wm * 96 + mi * 16 + fr][fg * 8];
      acc[mi][0] = MFMA(a, bfr[0], acc[mi][0]);
      acc[mi][1] = MFMA(a, bfr[1], acc[mi][1]);
    }
    __syncthreads();
  }

  // apply 1/z and stash as packed bf16 in registers
  uint2 pp[6][2];
#pragma unroll
  for (int mi = 0; mi < 6; ++mi)
#pragma unroll
    for (int ni = 0; ni < 2; ++ni) {
      const float z = zl[wn * 32 + ni * 16 + fr];
      unsigned a0 = ((unsigned)f2bits(acc[mi][ni][0] * z) & 0xffffu) |
                    (((unsigned)f2bits(acc[mi][ni][1] * z) & 0xffffu) << 16);
      unsigned a1 = ((unsigned)f2bits(acc[mi][ni][2] * z) & 0xffffu) |
                    (((unsigned)f2bits(acc[mi][ni][3] * z) & 0xffffu) << 16);
      pp[mi][ni] = make_uint2(a0, a1);
      acc[mi][ni] = (f32x4){0.f, 0.f, 0.f, 0.f};
    }

  // ---- gate = gw @ xs, K = 768
  for (int ks = 0; ks < 24; ++ks) {
    {
      const int o = t >> 2, cs = t & 3;
#pragma unroll
      for (int rr = 0; rr < 3; ++rr) {
        const int v = rr * 64 + o;
        const float* src = gw + (size_t)(vh * 192 + v) * A_ + ks * 32 + cs * 8;
        float4 v0 = *(const float4*)src;
        float4 v1 = *(const float4*)(src + 4);
        U8 r;
        r.s[0] = f2bits(v0.x); r.s[1] = f2bits(v0.y); r.s[2] = f2bits(v0.z); r.s[3] = f2bits(v0.w);
        r.s[4] = f2bits(v1.x); r.s[5] = f2bits(v1.y); r.s[6] = f2bits(v1.z); r.s[7] = f2bits(v1.w);
        *(bf16x8*)&Wa[v][cs * 8] = r.v;
      }
    }
    {
      const int n = t >> 2, aq = t & 3;
      *(bf16x8*)&Xt[n][aq * 8] = *(const bf16x8*)&yb[(size_t)n * A_ + ks * 32 + aq * 8];
    }
    __syncthreads();
    bf16x8 bfr[2];
#pragma unroll
    for (int ni = 0; ni < 2; ++ni) bfr[ni] = *(const bf16x8*)&Xt[wn * 32 + ni * 16 + fr][fg * 8];
#pragma unroll
    for (int mi = 0; mi < 6; ++mi) {
      bf16x8 a = *(const bf16x8*)&Wa[wm * 96 + mi * 16 + fr][fg * 8];
      acc[mi][0] = MFMA(a, bfr[0], acc[mi][0]);
      acc[mi][1] = MFMA(a, bfr[1], acc[mi][1]);
    }
    __syncthreads();
  }

  // ---- combine and write attnt[n][v]
#pragma unroll
  for (int mi = 0; mi < 6; ++mi) {
    const int vb = vh * 192 + wm * 96 + mi * 16 + fg * 4;
    const float g0 = gb[vb], g1 = gb[vb + 1], g2 = gb[vb + 2], g3 = gb[vb + 3];
#pragma unroll
    for (int ni = 0; ni < 2; ++ni) {
      const int n = n0 + wn * 32 + ni * 16 + fr;
      const uint2 p = pp[mi][ni];
      const float pv0 = bits2f((u16)(p.x & 0xffffu)), pv1 = bits2f((u16)(p.x >> 16));
      const float pv2 = bits2f((u16)(p.y & 0xffffu)), pv3 = bits2f((u16)(p.y >> 16));
      ushort4 o;
      o.x = f2bits(pv0 * sigm_f(acc[mi][ni][0] + g0));
      o.y = f2bits(pv1 * sigm_f(acc[mi][ni][1] + g1));
      o.z = f2bits(pv2 * sigm_f(acc[mi][ni][2] + g2));
      o.w = f2bits(pv3 * sigm_f(acc[mi][ni][3] + g3));
      *(ushort4*)&attnt[((size_t)b * N_ + n) * Vd + vb] = o;
    }
  }
}

// ============ K7: rms over v (384) per n, final combine (in place on attnt)
__global__ __launch_bounds__(256) void k_rmsfinal(const u16* __restrict__ yt,
                                                  const float* __restrict__ anw,
                                                  const float* __restrict__ svw,
                                                  u16* __restrict__ attnt) {
  const int b = blockIdx.y;
  const int n0 = blockIdx.x * 32;
  const int t = threadIdx.x;
  __shared__ float anws[384], svws[384];
  for (int i = t; i < 384; i += 256) {
    anws[i] = anw[i];
    svws[i] = svw[i];
  }
  __syncthreads();
  const int n = n0 + (t >> 3);
  const int vs = (t & 7) * 8;
  u16* ap = attnt + ((size_t)b * N_ + n) * Vd;
  U8 av[6];
  float ss = 0.f;
#pragma unroll
  for (int j = 0; j < 6; ++j) {
    av[j].v = *(const bf16x8*)&ap[vs + j * 64];
#pragma unroll
    for (int i = 0; i < 8; ++i) {
      const float f = bits2f(av[j].s[i]);
      ss = fmaf(f, f, ss);
    }
  }
  ss += __shfl_xor(ss, 1);
  ss += __shfl_xor(ss, 2);
  ss += __shfl_xor(ss, 4);
  const float rinv = rsqrtf(ss * (1.0f / (float)Vd) + EPSf);
  const u16* vp = yt + ((size_t)b * N_ + n) * A_ + 2 * Dq;
#pragma unroll
  for (int j = 0; j < 6; ++j) {
    U8 vv, o;
    vv.v = *(const bf16x8*)&vp[vs + j * 64];
#pragma unroll
    for (int i = 0; i < 8; ++i) {
      const int v = vs + j * 64 + i;
      const float val = bits2f(av[j].s[i]) * rinv * anws[v] + bits2f(vv.s[i]) * svws[v];
      o.s[i] = f2bits(val);
    }
    *(bf16x8*)&ap[vs + j * 64] = o.v;
  }
}

// ============ K8: out GEMM  out[b][c][n] = sum_v ow[c,v]*attnt[n][v] + ob[c]
__global__ __launch_bounds__(256, 2) void k_out(const u16* __restrict__ attnt,
                                                const float* __restrict__ ow,
                                                const float* __restrict__ ob,
                                                float* __restrict__ out) {
  const int n0 = blockIdx.x * 64;
  const int b = blockIdx.y;
  __shared__ u16 Xt[64][392];  // [n][v] full K, stride 784B
  __shared__ u16 Wa[64][40];
  const int t = threadIdx.x;
  const int lane = t & 63, wid = t >> 6, wm = wid >> 1, wn = wid & 1;
  const int fr = lane & 15, fg = lane >> 4;
  {
    const int n = t >> 2, aq = t & 3;
    const u16* src = attnt + ((size_t)b * N_ + n0 + n) * Vd + aq * 8;
#pragma unroll
    for (int vr = 0; vr < 12; ++vr)
      *(bf16x8*)&Xt[n][vr * 32 + aq * 8] = *(const bf16x8*)&src[vr * 32];
  }
  f32x4 acc[2][2];
  for (int cb = 0; cb < 3; ++cb) {
#pragma unroll
    for (int mi = 0; mi < 2; ++mi)
#pragma unroll
      for (int ni = 0; ni < 2; ++ni) acc[mi][ni] = (f32x4){0.f, 0.f, 0.f, 0.f};
    for (int ks = 0; ks < 12; ++ks) {
      {
        const int o = t >> 2, cs = t & 3;
        const float* src = ow + (size_t)(cb * 64 + o) * Vd + ks * 32 + cs * 8;
        float4 v0 = *(const float4*)src;
        float4 v1 = *(const float4*)(src + 4);
        U8 r;
        r.s[0] = f2bits(v0.x); r.s[1] = f2bits(v0.y); r.s[2] = f2bits(v0.z); r.s[3] = f2bits(v0.w);
        r.s[4] = f2bits(v1.x); r.s[5] = f2bits(v1.y); r.s[6] = f2bits(v1.z); r.s[7] = f2bits(v1.w);
        *(bf16x8*)&Wa[o][cs * 8] = r.v;
      }
      __syncthreads();
      bf16x8 a0 = *(const bf16x8*)&Wa[wm * 32 + fr][fg * 8];
      bf16x8 a1 = *(const bf16x8*)&Wa[wm * 32 + 16 + fr][fg * 8];
      bf16x8 b0 = *(const bf16x8*)&Xt[wn * 32 + fr][ks * 32 + fg * 8];
      bf16x8 b1 = *(const bf16x8*)&Xt[wn * 32 + 16 + fr][ks * 32 + fg * 8];
      acc[0][0] = MFMA(a0, b0, acc[0][0]);
      acc[0][1] = MFMA(a0, b1, acc[0][1]);
      acc[1][0] = MFMA(a1, b0, acc[1][0]);
      acc[1][1] = MFMA(a1, b1, acc[1][1]);
      __syncthreads();
    }
#pragma unroll
    for (int mi = 0; mi < 2; ++mi) {
      const int c = cb * 64 + wm * 32 + mi * 16 + fg * 4;
      const float b0 = ob[c], b1 = ob[c + 1], b2 = ob[c + 2], b3 = ob[c + 3];
#pragma unroll
      for (int ni = 0; ni < 2; ++ni) {
        const int n = n0 + wn * 32 + ni * 16 + fr;
        float* o = out + ((size_t)b * C_ + c) * N_ + n;
        o[0 * N_] = acc[mi][ni][0] + b0;
        o[1 * N_] = acc[mi][ni][1] + b1;
        o[2 * N_] = acc[mi][ni][2] + b2;
        o[3 * N_] = acc[mi][ni][3] + b3;
      }
    }
  }
}

extern "C" void kernel_launch(void* const* d_in, const int* in_sizes, int n_in,
                              void* d_out, int out_size, void* d_ws, size_t ws_size,
                              hipStream_t stream) {
  (void)in_sizes; (void)n_in; (void)out_size; (void)ws_size;
  const float* x = (const float*)d_in[0];
  const float* pw = (const float*)d_in[1];
  const float* pb = (const float*)d_in[2];
  const float* cw = (const float*)d_in[3];
  const float* cb = (const float*)d_in[4];
  const float* gw = (const float*)d_in[5];
  const float* gb = (const float*)d_in[6];
  const float* anw = (const float*)d_in[7];
  const float* svw = (const float*)d_in[8];
  const float* ow = (const float*)d_in[9];
  const float* ob = (const float*)d_in[10];
  float* out = (float*)d_out;

  char* ws = (char*)d_ws;
  const size_t szY = (size_t)B_ * N_ * A_ * 2;  // 77,070,336 B
  u16* y0t = (u16*)(ws);                        // [B][N][A] bf16 (later aliased by attnt)
  u16* yt = (u16*)(ws + szY);                   // [B][N][A] bf16
  float* kfp = (float*)(ws + 2 * szY);          // [7][B][192] f32 (86,016 B)
  float* zinv = (float*)(ws + 2 * szY + 86016);           // [B][N] f32 (200,704 B)
  float* vkp = (float*)(ws + 2 * szY + 86016 + 200704);   // [B][384][192] f32
  u16* attnt = y0t;                             // [B][N][Vd] bf16, aliases y0t (dead)

  k_proj<<<dim3(49, 16), 256, 0, stream>>>(x, pw, pb, y0t);
  k_dwc<<<dim3(2688), 256, 0, stream>>>(y0t, cw, cb, yt);
  k_kfmean<<<dim3(7, 3, 16), 256, 0, stream>>>(yt, kfp);
  k_z<<<dim3(13, 16), 256, 0, stream>>>(yt, kfp, zinv);
  k_vk<<<dim3(288), 256, 0, stream>>>(yt, vkp);
  k_gateattn<<<dim3(1568), 256, 0, stream>>>(yt, zinv, vkp, gw, gb, attnt);
  k_rmsfinal<<<dim3(98, 16), 256, 0, stream>>>(yt, anw, svw, attnt);
  k_out<<<dim3(49, 16), 256, 0, stream>>>(attnt, ow, ob, out);
}

// Round 3
// 316.482 us; speedup vs baseline: 4.8563x; 1.3693x over previous
//
#include <hip/hip_runtime.h>
#include <hip/hip_bf16.h>

typedef unsigned short u16;
typedef __attribute__((ext_vector_type(8))) short bf16x8;
typedef __attribute__((ext_vector_type(4))) float f32x4;

constexpr int B_ = 16, C_ = 192, H_ = 56, W_ = 56;
constexpr int N_ = H_ * W_;   // 3136
constexpr int A_ = 768;       // attn_dim
constexpr int Dq = 192;       // d_qk
constexpr int Vd = 384;       // d_v
constexpr float EPSf = 1e-6f;

union U8 { bf16x8 v; u16 s[8]; unsigned u[4]; };

__device__ __forceinline__ float bits2f(u16 u) {
  return __uint_as_float(((unsigned)u) << 16);
}
__device__ __forceinline__ u16 f2bits(float f) {
  __hip_bfloat16 h = __float2bfloat16(f);
  u16 u;
  __builtin_memcpy(&u, &h, sizeof(u));
  return u;
}
__device__ __forceinline__ float silu_f(float v) { return v / (1.0f + __expf(-v)); }
__device__ __forceinline__ float sigm_f(float v) { return 1.0f / (1.0f + __expf(-v)); }

__device__ __forceinline__ f32x4 MFMA(bf16x8 a, bf16x8 b, f32x4 c) {
  return __builtin_amdgcn_mfma_f32_16x16x32_bf16(a, b, c, 0, 0, 0);
}

// ============ K0: weight pre-convert f32 -> bf16 (pw, gw, ow)
__global__ __launch_bounds__(256) void k_prep(const float* __restrict__ pw,
                                              const float* __restrict__ gw,
                                              const float* __restrict__ ow,
                                              u16* __restrict__ pwb,
                                              u16* __restrict__ gwb,
                                              u16* __restrict__ owb) {
  const int bid = blockIdx.x;
  const size_t base = ((size_t)bid * 256 + threadIdx.x) * 8;
  const float* src;
  u16* dst;
  size_t off;
  if (bid < 72) { src = pw; dst = pwb; off = base; }
  else if (bid < 216) { src = gw; dst = gwb; off = base - 147456; }
  else { src = ow; dst = owb; off = base - 442368; }
  float4 v0 = *(const float4*)&src[off];
  float4 v1 = *(const float4*)&src[off + 4];
  U8 r;
  r.s[0] = f2bits(v0.x); r.s[1] = f2bits(v0.y); r.s[2] = f2bits(v0.z); r.s[3] = f2bits(v0.w);
  r.s[4] = f2bits(v1.x); r.s[5] = f2bits(v1.y); r.s[6] = f2bits(v1.z); r.s[7] = f2bits(v1.w);
  *(bf16x8*)&dst[off] = r.v;
}

// ============ K1: proj GEMM  y0t[b][n][o] = sum_c pw[o,c]*x[b,c,n] + pb[o]
// block: 256 o x 64 n. Xt persistent (K=192), Wa swizzled per-ks.
__global__ __launch_bounds__(256) void k_proj(const float* __restrict__ x,
                                              const u16* __restrict__ pwb,
                                              const float* __restrict__ pb,
                                              u16* __restrict__ y0t) {
  const int n0 = blockIdx.x * 64;
  const int oy = blockIdx.y;  // 0..2
  const int b = blockIdx.z;
  __shared__ u16 Xt[64][200];  // [n][c], 400B stride (16B mult)
  __shared__ u16 Wa[256][32];  // [o][k32], swizzled 16B blocks
  const int t = threadIdx.x;
  const int lane = t & 63, wid = t >> 6;
  const int fr = lane & 15, fg = lane >> 4;

  // stage Xt: x[b][c][n] -> Xt[n][c]
  {
    const int p = t & 31, co = t >> 5;
    const float* xb = x + (size_t)b * C_ * N_ + n0 + 2 * p;
#pragma unroll
    for (int rnd = 0; rnd < 3; ++rnd) {
      const int c0 = rnd * 64 + co * 8;
      float2 v[8];
#pragma unroll
      for (int i = 0; i < 8; ++i) v[i] = *(const float2*)&xb[(size_t)(c0 + i) * N_];
      U8 r0, r1;
#pragma unroll
      for (int i = 0; i < 8; ++i) { r0.s[i] = f2bits(v[i].x); r1.s[i] = f2bits(v[i].y); }
      *(bf16x8*)&Xt[2 * p][c0] = r0.v;
      *(bf16x8*)&Xt[2 * p + 1][c0] = r1.v;
    }
  }

  f32x4 acc[4][4];
#pragma unroll
  for (int mi = 0; mi < 4; ++mi)
#pragma unroll
    for (int ni = 0; ni < 4; ++ni) acc[mi][ni] = (f32x4){0.f, 0.f, 0.f, 0.f};

  const int orow_c = t >> 2, oct_c = t & 3;
  for (int ks = 0; ks < 6; ++ks) {
    __syncthreads();  // Wa overwrite guard (also covers Xt on first iter)
#pragma unroll
    for (int jj = 0; jj < 4; ++jj) {
      const int orow = orow_c + 64 * jj;
      const int sw = (orow >> 1) & 3;
      bf16x8 v = *(const bf16x8*)&pwb[(size_t)(oy * 256 + orow) * C_ + ks * 32 + oct_c * 8];
      *(bf16x8*)&Wa[orow][(oct_c ^ sw) * 8] = v;
    }
    __syncthreads();
    bf16x8 bfrag[4];
#pragma unroll
    for (int ni = 0; ni < 4; ++ni)
      bfrag[ni] = *(const bf16x8*)&Xt[ni * 16 + fr][ks * 32 + fg * 8];
#pragma unroll
    for (int mi = 0; mi < 4; ++mi) {
      const int ar = wid * 64 + mi * 16 + fr;
      bf16x8 a = *(const bf16x8*)&Wa[ar][(fg ^ ((ar >> 1) & 3)) * 8];
#pragma unroll
      for (int ni = 0; ni < 4; ++ni) acc[mi][ni] = MFMA(a, bfrag[ni], acc[mi][ni]);
    }
  }
#pragma unroll
  for (int mi = 0; mi < 4; ++mi) {
    const int o4 = oy * 256 + wid * 64 + mi * 16 + fg * 4;
    const float b0 = pb[o4], b1 = pb[o4 + 1], b2 = pb[o4 + 2], b3 = pb[o4 + 3];
#pragma unroll
    for (int ni = 0; ni < 4; ++ni) {
      const int n = n0 + ni * 16 + fr;
      ushort4 pk;
      pk.x = f2bits(acc[mi][ni][0] + b0);
      pk.y = f2bits(acc[mi][ni][1] + b1);
      pk.z = f2bits(acc[mi][ni][2] + b2);
      pk.w = f2bits(acc[mi][ni][3] + b3);
      *(ushort4*)&y0t[((size_t)b * N_ + n) * A_ + o4] = pk;
    }
  }
}

// ============ K2: depthwise 3x3 + bias + residual; also writes skq = silu(y[:, :384])
__global__ __launch_bounds__(256) void k_dwc(const u16* __restrict__ y0t,
                                             const float* __restrict__ cw,
                                             const float* __restrict__ cb,
                                             u16* __restrict__ yt,
                                             u16* __restrict__ skq) {
  const int pid = blockIdx.x;
  const int L = (pid & 7) * 336 + (pid >> 3);  // 2688 = 8*336
  const int h = L % 56, at = (L / 56) % 3, b = L / 168;
  const int t = threadIdx.x;
  const int a = at * 256 + (t & 31) * 8;
  const int wl = t >> 5;
  float w9[9][8];
  float bias[8];
#pragma unroll
  for (int j = 0; j < 8; ++j) {
    bias[j] = cb[a + j];
#pragma unroll
    for (int k = 0; k < 9; ++k) w9[k][j] = cw[(a + j) * 9 + k];
  }
  const u16* src = y0t + (size_t)b * N_ * A_ + a;
  u16* dst = yt + (size_t)b * N_ * A_ + a;
  const bool hok0 = h > 0, hok2 = h < 55;
  for (int wc = 0; wc < 7; ++wc) {
    const int w = wc * 8 + wl;
    const bool wok0 = w > 0, wok2 = w < 55;
    U8 nb[9];
#pragma unroll
    for (int dh = -1; dh <= 1; ++dh) {
      const bool hok = (dh == -1) ? hok0 : ((dh == 1) ? hok2 : true);
#pragma unroll
      for (int dw = -1; dw <= 1; ++dw) {
        const int k = (dh + 1) * 3 + (dw + 1);
        const bool ok = hok && ((dw == -1) ? wok0 : ((dw == 1) ? wok2 : true));
        if (ok)
          nb[k].v = *(const bf16x8*)&src[(size_t)((h + dh) * 56 + (w + dw)) * A_];
        else
          nb[k].u[0] = nb[k].u[1] = nb[k].u[2] = nb[k].u[3] = 0u;
      }
    }
    U8 o;
    float sv[8];
#pragma unroll
    for (int j = 0; j < 8; ++j) {
      float s = bias[j] + bits2f(nb[4].s[j]);
#pragma unroll
      for (int k = 0; k < 9; ++k) s = fmaf(w9[k][j], bits2f(nb[k].s[j]), s);
      sv[j] = s;
      o.s[j] = f2bits(s);
    }
    *(bf16x8*)&dst[(size_t)(h * 56 + w) * A_] = o.v;
    if (a < 384) {
      U8 q;
#pragma unroll
      for (int j = 0; j < 8; ++j) q.s[j] = f2bits(silu_f(sv[j]));
      *(bf16x8*)&skq[((size_t)b * N_ + h * 56 + w) * 384 + a] = q.v;
    }
  }
}

// ============ K3: kfmean partials from skq k-part (pre-silu'd)
__global__ __launch_bounds__(256) void k_kfmean(const u16* __restrict__ skq,
                                                float* __restrict__ kfp) {
  const int ns = blockIdx.x, dc = blockIdx.y, b = blockIdx.z;
  const int t = threadIdx.x;
  const int dq = t & 15, nw = t >> 4;
  const u16* p = skq + ((size_t)b * N_ + ns * 448 + nw) * 384 + 192 + dc * 64 + dq * 4;
  float s0 = 0, s1 = 0, s2 = 0, s3 = 0;
#pragma unroll 4
  for (int i = 0; i < 28; ++i) {
    ushort4 u = *(const ushort4*)&p[(size_t)i * 16 * 384];
    s0 += bits2f(u.x);
    s1 += bits2f(u.y);
    s2 += bits2f(u.z);
    s3 += bits2f(u.w);
  }
  __shared__ float red[16][65];
  red[nw][dq * 4 + 0] = s0;
  red[nw][dq * 4 + 1] = s1;
  red[nw][dq * 4 + 2] = s2;
  red[nw][dq * 4 + 3] = s3;
  __syncthreads();
  if (t < 64) {
    float s = 0;
#pragma unroll
    for (int i = 0; i < 16; ++i) s += red[i][t];
    kfp[((size_t)ns * B_ + b) * Dq + dc * 64 + t] = s * (1.0f / (float)N_);
  }
}

// ============ K4: zinv[b][n] = 1/(sum_d kfm[d]*qf[n,d] + EPS)  (qf from skq)
__global__ __launch_bounds__(256) void k_z(const u16* __restrict__ skq,
                                           const float* __restrict__ kfp,
                                           float* __restrict__ zinv) {
  const int b = blockIdx.y;
  const int n = blockIdx.x * 256 + threadIdx.x;
  __shared__ float kf[192];
  if (threadIdx.x < 192) {
    float s = 0;
#pragma unroll
    for (int ns = 0; ns < 7; ++ns) s += kfp[((size_t)ns * B_ + b) * Dq + threadIdx.x];
    kf[threadIdx.x] = s;
  }
  __syncthreads();
  if (n < N_) {
    const u16* p = skq + ((size_t)b * N_ + n) * 384;
    float z = 0;
#pragma unroll
    for (int j = 0; j < 24; ++j) {
      U8 u;
      u.v = *(const bf16x8*)&p[j * 8];
#pragma unroll
      for (int i = 0; i < 8; ++i) z = fmaf(kf[j * 8 + i], bits2f(u.s[i]), z);
    }
    zinv[(size_t)b * N_ + n] = 1.0f / (z + EPSf);
  }
}

// ============ K5: vk GEMM, split-K over N (7 chunks), 128v x 192d tiles.
// LDS: unified 320-row transposed tile, XOR-swizzled, partials in f32.
__global__ __launch_bounds__(256) void k_vk(const u16* __restrict__ skq,
                                            const u16* __restrict__ yt,
                                            float* __restrict__ vkpart) {
  const int pid = blockIdx.x;  // 336 = 8*42
  const int L = (pid & 7) * 42 + (pid >> 3);
  const int ns = L % 7;
  const int vblk = (L / 7) % 3;
  const int b = L / 21;
  const int t = threadIdx.x;
  const int lane = t & 63, wid = t >> 6;
  const int fr = lane & 15, fg = lane >> 4;
  const int vbase = (wid >> 1) * 64, dbase = (wid & 1) * 96;

  __shared__ u16 T[320 * 64];  // rows 0..191: K(d); rows 192..319: V
  unsigned* T32 = (unsigned*)T;

  const int oct0 = t & 7;
  const int pair = (t >> 3) & 31;
  const int nb0 = ns * 448;

  U8 pre[5][2];
  auto load_pre = [&](int n0) {
    const int n = nb0 + n0 + pair * 2;
#pragma unroll
    for (int j = 0; j < 5; ++j) {
      const int oct = oct0 + 8 * j;
      const u16* srcp;
      size_t stride;
      if (j < 3) {
        srcp = skq + ((size_t)b * N_ + n) * 384 + 192 + oct * 8;
        stride = 384;
      } else {
        srcp = yt + ((size_t)b * N_ + n) * A_ + 384 + vblk * 128 + (oct - 24) * 8;
        stride = A_;
      }
      pre[j][0].v = *(const bf16x8*)srcp;
      pre[j][1].v = *(const bf16x8*)(srcp + stride);
    }
  };

  f32x4 acc[4][6];
#pragma unroll
  for (int mi = 0; mi < 4; ++mi)
#pragma unroll
    for (int ni = 0; ni < 6; ++ni) acc[mi][ni] = (f32x4){0.f, 0.f, 0.f, 0.f};

  load_pre(0);
  for (int s = 0; s < 7; ++s) {
    __syncthreads();  // prior MFMA done reading T
#pragma unroll
    for (int j = 0; j < 5; ++j) {
      const int rowb = (oct0 + 8 * j) * 8;
#pragma unroll
      for (int i = 0; i < 8; ++i) {
        const int row = rowb + i;
        const int sw = (row & 7) ^ ((row >> 3) & 7);
        const unsigned val =
            ((unsigned)pre[j][0].s[i] & 0xffffu) | (((unsigned)pre[j][1].s[i]) << 16);
        T32[row * 32 + (pair ^ (sw << 2))] = val;
      }
    }
    __syncthreads();
    if (s < 6) load_pre((s + 1) * 64);  // prefetch next step under MFMA
#pragma unroll
    for (int kf2 = 0; kf2 < 2; ++kf2) {
      bf16x8 bfrag[6];
#pragma unroll
      for (int ni = 0; ni < 6; ++ni) {
        const int row = dbase + ni * 16 + fr;
        const int sw = (row & 7) ^ ((row >> 3) & 7);
        bfrag[ni] = *(const bf16x8*)&T[row * 64 + ((kf2 * 32 + fg * 8) ^ (sw << 3))];
      }
#pragma unroll
      for (int mi = 0; mi < 4; ++mi) {
        const int row = 192 + vbase + mi * 16 + fr;
        const int sw = (row & 7) ^ ((row >> 3) & 7);
        bf16x8 a = *(const bf16x8*)&T[row * 64 + ((kf2 * 32 + fg * 8) ^ (sw << 3))];
#pragma unroll
        for (int ni = 0; ni < 6; ++ni) acc[mi][ni] = MFMA(a, bfrag[ni], acc[mi][ni]);
      }
    }
  }
  float* base = vkpart + (((size_t)ns * 16 + b) * 3 + vblk) * (128 * 192);
#pragma unroll
  for (int mi = 0; mi < 4; ++mi)
#pragma unroll
    for (int ni = 0; ni < 6; ++ni) {
      const int v = vbase + mi * 16 + fg * 4;
      const int d = dbase + ni * 16 + fr;
      float* o = base + (size_t)v * 192 + d;
      o[0] = acc[mi][ni][0];
      o[192] = acc[mi][ni][1];
      o[384] = acc[mi][ni][2];
      o[576] = acc[mi][ni][3];
    }
}

// ============ K5b: reduce 7 partials -> vkb bf16 [b][384][192] (with 1/N)
__global__ __launch_bounds__(256) void k_vkred(const float* __restrict__ vkpart,
                                               u16* __restrict__ vkb) {
  const size_t e = ((size_t)blockIdx.x * 256 + threadIdx.x) * 8;
  constexpr size_t NSSTRIDE = (size_t)16 * 3 * 128 * 192;
  float4 s0 = {0, 0, 0, 0}, s1 = {0, 0, 0, 0};
#pragma unroll
  for (int ns = 0; ns < 7; ++ns) {
    float4 a0 = *(const float4*)&vkpart[ns * NSSTRIDE + e];
    float4 a1 = *(const float4*)&vkpart[ns * NSSTRIDE + e + 4];
    s0.x += a0.x; s0.y += a0.y; s0.z += a0.z; s0.w += a0.w;
    s1.x += a1.x; s1.y += a1.y; s1.z += a1.z; s1.w += a1.w;
  }
  const float sc = 1.0f / (float)N_;
  U8 r;
  r.s[0] = f2bits(s0.x * sc); r.s[1] = f2bits(s0.y * sc);
  r.s[2] = f2bits(s0.z * sc); r.s[3] = f2bits(s0.w * sc);
  r.s[4] = f2bits(s1.x * sc); r.s[5] = f2bits(s1.y * sc);
  r.s[6] = f2bits(s1.z * sc); r.s[7] = f2bits(s1.w * sc);
  *(bf16x8*)&vkb[e] = r.v;
}

// ============ K6: fused attn0 (vkb@qf /z) and gate (sigmoid(gwb@xs+gb)); writes attnt[n][v]
__global__ __launch_bounds__(256, 3) void k_gateattn(const u16* __restrict__ yt,
                                                     const u16* __restrict__ skq,
                                                     const float* __restrict__ zinv,
                                                     const u16* __restrict__ vkb,
                                                     const u16* __restrict__ gwb,
                                                     const float* __restrict__ gb,
                                                     u16* __restrict__ attnt) {
  const int pid = blockIdx.x;
  const int L = (pid & 7) * 196 + (pid >> 3);  // 1568 = 8*196
  const int vh = L & 1;
  const int n0 = ((L >> 1) % 49) * 64;
  const int b = L / 98;
  const int t = threadIdx.x;
  const int lane = t & 63, wid = t >> 6, wm = wid >> 1, wn = wid & 1;
  const int fr = lane & 15, fg = lane >> 4;
  __shared__ u16 Wa[192][40];
  __shared__ u16 Xt[64][40];
  __shared__ float zl[64];
  if (t < 64) zl[t] = zinv[(size_t)b * N_ + n0 + t];
  const u16* yb = yt + ((size_t)b * N_ + n0) * A_;
  const u16* qb = skq + ((size_t)b * N_ + n0) * 384;

  f32x4 acc[6][2];
#pragma unroll
  for (int mi = 0; mi < 6; ++mi)
#pragma unroll
    for (int ni = 0; ni < 2; ++ni) acc[mi][ni] = (f32x4){0.f, 0.f, 0.f, 0.f};

  // ---- attn0 = vkb @ qf, K = 192
  for (int ks = 0; ks < 6; ++ks) {
    {
      const int o = t >> 2, cs = t & 3;
#pragma unroll
      for (int rr = 0; rr < 3; ++rr) {
        const int v = rr * 64 + o;
        *(bf16x8*)&Wa[v][cs * 8] =
            *(const bf16x8*)&vkb[((size_t)(vh * 192 + v) + 0) * 0 +
                                 ((size_t)b * Vd + vh * 192 + v) * 192 + ks * 32 + cs * 8];
      }
    }
    {
      const int n = t >> 2, aq = t & 3;
      *(bf16x8*)&Xt[n][aq * 8] = *(const bf16x8*)&qb[(size_t)n * 384 + ks * 32 + aq * 8];
    }
    __syncthreads();
    bf16x8 bfr[2];
#pragma unroll
    for (int ni = 0; ni < 2; ++ni) bfr[ni] = *(const bf16x8*)&Xt[wn * 32 + ni * 16 + fr][fg * 8];
#pragma unroll
    for (int mi = 0; mi < 6; ++mi) {
      bf16x8 a = *(const bf16x8*)&Wa[wm * 96 + mi * 16 + fr][fg * 8];
      acc[mi][0] = MFMA(a, bfr[0], acc[mi][0]);
      acc[mi][1] = MFMA(a, bfr[1], acc[mi][1]);
    }
    __syncthreads();
  }

  // apply 1/z and stash as packed bf16 in registers
  uint2 pp[6][2];
#pragma unroll
  for (int mi = 0; mi < 6; ++mi)
#pragma unroll
    for (int ni = 0; ni < 2; ++ni) {
      const float z = zl[wn * 32 + ni * 16 + fr];
      unsigned a0 = ((unsigned)f2bits(acc[mi][ni][0] * z) & 0xffffu) |
                    (((unsigned)f2bits(acc[mi][ni][1] * z) & 0xffffu) << 16);
      unsigned a1 = ((unsigned)f2bits(acc[mi][ni][2] * z) & 0xffffu) |
                    (((unsigned)f2bits(acc[mi][ni][3] * z) & 0xffffu) << 16);
      pp[mi][ni] = make_uint2(a0, a1);
      acc[mi][ni] = (f32x4){0.f, 0.f, 0.f, 0.f};
    }

  // ---- gate = gwb @ xs, K = 768
  for (int ks = 0; ks < 24; ++ks) {
    {
      const int o = t >> 2, cs = t & 3;
#pragma unroll
      for (int rr = 0; rr < 3; ++rr) {
        const int v = rr * 64 + o;
        *(bf16x8*)&Wa[v][cs * 8] =
            *(const bf16x8*)&gwb[(size_t)(vh * 192 + v) * A_ + ks * 32 + cs * 8];
      }
    }
    {
      const int n = t >> 2, aq = t & 3;
      *(bf16x8*)&Xt[n][aq * 8] = *(const bf16x8*)&yb[(size_t)n * A_ + ks * 32 + aq * 8];
    }
    __syncthreads();
    bf16x8 bfr[2];
#pragma unroll
    for (int ni = 0; ni < 2; ++ni) bfr[ni] = *(const bf16x8*)&Xt[wn * 32 + ni * 16 + fr][fg * 8];
#pragma unroll
    for (int mi = 0; mi < 6; ++mi) {
      bf16x8 a = *(const bf16x8*)&Wa[wm * 96 + mi * 16 + fr][fg * 8];
      acc[mi][0] = MFMA(a, bfr[0], acc[mi][0]);
      acc[mi][1] = MFMA(a, bfr[1], acc[mi][1]);
    }
    __syncthreads();
  }

  // ---- combine and write attnt[n][v]
#pragma unroll
  for (int mi = 0; mi < 6; ++mi) {
    const int vb = vh * 192 + wm * 96 + mi * 16 + fg * 4;
    const float g0 = gb[vb], g1 = gb[vb + 1], g2 = gb[vb + 2], g3 = gb[vb + 3];
#pragma unroll
    for (int ni = 0; ni < 2; ++ni) {
      const int n = n0 + wn * 32 + ni * 16 + fr;
      const uint2 p = pp[mi][ni];
      const float pv0 = bits2f((u16)(p.x & 0xffffu)), pv1 = bits2f((u16)(p.x >> 16));
      const float pv2 = bits2f((u16)(p.y & 0xffffu)), pv3 = bits2f((u16)(p.y >> 16));
      ushort4 o;
      o.x = f2bits(pv0 * sigm_f(acc[mi][ni][0] + g0));
      o.y = f2bits(pv1 * sigm_f(acc[mi][ni][1] + g1));
      o.z = f2bits(pv2 * sigm_f(acc[mi][ni][2] + g2));
      o.w = f2bits(pv3 * sigm_f(acc[mi][ni][3] + g3));
      *(ushort4*)&attnt[((size_t)b * N_ + n) * Vd + vb] = o;
    }
  }
}

// ============ K7: rms over v (384) per n, final combine (in place on attnt)
__global__ __launch_bounds__(256) void k_rmsfinal(const u16* __restrict__ yt,
                                                  const float* __restrict__ anw,
                                                  const float* __restrict__ svw,
                                                  u16* __restrict__ attnt) {
  const int b = blockIdx.y;
  const int n0 = blockIdx.x * 32;
  const int t = threadIdx.x;
  __shared__ float anws[384], svws[384];
  for (int i = t; i < 384; i += 256) {
    anws[i] = anw[i];
    svws[i] = svw[i];
  }
  __syncthreads();
  const int n = n0 + (t >> 3);
  const int vs = (t & 7) * 8;
  u16* ap = attnt + ((size_t)b * N_ + n) * Vd;
  U8 av[6];
  float ss = 0.f;
#pragma unroll
  for (int j = 0; j < 6; ++j) {
    av[j].v = *(const bf16x8*)&ap[vs + j * 64];
#pragma unroll
    for (int i = 0; i < 8; ++i) {
      const float f = bits2f(av[j].s[i]);
      ss = fmaf(f, f, ss);
    }
  }
  ss += __shfl_xor(ss, 1);
  ss += __shfl_xor(ss, 2);
  ss += __shfl_xor(ss, 4);
  const float rinv = rsqrtf(ss * (1.0f / (float)Vd) + EPSf);
  const u16* vp = yt + ((size_t)b * N_ + n) * A_ + 2 * Dq;
#pragma unroll
  for (int j = 0; j < 6; ++j) {
    U8 vv, o;
    vv.v = *(const bf16x8*)&vp[vs + j * 64];
#pragma unroll
    for (int i = 0; i < 8; ++i) {
      const int v = vs + j * 64 + i;
      const float val = bits2f(av[j].s[i]) * rinv * anws[v] + bits2f(vv.s[i]) * svws[v];
      o.s[i] = f2bits(val);
    }
    *(bf16x8*)&ap[vs + j * 64] = o.v;
  }
}

// ============ K8: out GEMM  out[b][c][n] = sum_v ow[c,v]*attnt[n][v] + ob[c]
__global__ __launch_bounds__(256, 2) void k_out(const u16* __restrict__ attnt,
                                                const u16* __restrict__ owb,
                                                const float* __restrict__ ob,
                                                float* __restrict__ out) {
  const int n0 = blockIdx.x * 64;
  const int b = blockIdx.y;
  __shared__ u16 Xt[64][392];
  __shared__ u16 Wa[64][40];
  const int t = threadIdx.x;
  const int lane = t & 63, wid = t >> 6, wm = wid >> 1, wn = wid & 1;
  const int fr = lane & 15, fg = lane >> 4;
  {
    const int n = t >> 2, aq = t & 3;
    const u16* src = attnt + ((size_t)b * N_ + n0 + n) * Vd + aq * 8;
#pragma unroll
    for (int vr = 0; vr < 12; ++vr)
      *(bf16x8*)&Xt[n][vr * 32 + aq * 8] = *(const bf16x8*)&src[vr * 32];
  }
  f32x4 acc[2][2];
  for (int cb = 0; cb < 3; ++cb) {
#pragma unroll
    for (int mi = 0; mi < 2; ++mi)
#pragma unroll
      for (int ni = 0; ni < 2; ++ni) acc[mi][ni] = (f32x4){0.f, 0.f, 0.f, 0.f};
    for (int ks = 0; ks < 12; ++ks) {
      {
        const int o = t >> 2, cs = t & 3;
        *(bf16x8*)&Wa[o][cs * 8] =
            *(const bf16x8*)&owb[(size_t)(cb * 64 + o) * Vd + ks * 32 + cs * 8];
      }
      __syncthreads();
      bf16x8 a0 = *(const bf16x8*)&Wa[wm * 32 + fr][fg * 8];
      bf16x8 a1 = *(const bf16x8*)&Wa[wm * 32 + 16 + fr][fg * 8];
      bf16x8 b0 = *(const bf16x8*)&Xt[wn * 32 + fr][ks * 32 + fg * 8];
      bf16x8 b1 = *(const bf16x8*)&Xt[wn * 32 + 16 + fr][ks * 32 + fg * 8];
      acc[0][0] = MFMA(a0, b0, acc[0][0]);
      acc[0][1] = MFMA(a0, b1, acc[0][1]);
      acc[1][0] = MFMA(a1, b0, acc[1][0]);
      acc[1][1] = MFMA(a1, b1, acc[1][1]);
      __syncthreads();
    }
#pragma unroll
    for (int mi = 0; mi < 2; ++mi) {
      const int c = cb * 64 + wm * 32 + mi * 16 + fg * 4;
      const float b0 = ob[c], b1 = ob[c + 1], b2 = ob[c + 2], b3 = ob[c + 3];
#pragma unroll
      for (int ni = 0; ni < 2; ++ni) {
        const int n = n0 + wn * 32 + ni * 16 + fr;
        float* o = out + ((size_t)b * C_ + c) * N_ + n;
        o[0 * N_] = acc[mi][ni][0] + b0;
        o[1 * N_] = acc[mi][ni][1] + b1;
        o[2 * N_] = acc[mi][ni][2] + b2;
        o[3 * N_] = acc[mi][ni][3] + b3;
      }
    }
  }
}

extern "C" void kernel_launch(void* const* d_in, const int* in_sizes, int n_in,
                              void* d_out, int out_size, void* d_ws, size_t ws_size,
                              hipStream_t stream) {
  (void)in_sizes; (void)n_in; (void)out_size; (void)ws_size;
  const float* x = (const float*)d_in[0];
  const float* pw = (const float*)d_in[1];
  const float* pb = (const float*)d_in[2];
  const float* cw = (const float*)d_in[3];
  const float* cb = (const float*)d_in[4];
  const float* gw = (const float*)d_in[5];
  const float* gb = (const float*)d_in[6];
  const float* anw = (const float*)d_in[7];
  const float* svw = (const float*)d_in[8];
  const float* ow = (const float*)d_in[9];
  const float* ob = (const float*)d_in[10];
  float* out = (float*)d_out;

  char* ws = (char*)d_ws;
  const size_t szY = (size_t)B_ * N_ * A_ * 2;  // 77,070,336
  // Region R0 (0..szY): y0t until k_dwc; then attnt / vkpart / vkb.
  u16* y0t = (u16*)(ws);
  u16* attnt = (u16*)(ws);                          // [B][N][384] bf16 (38,535,168)
  float* vkpart = (float*)(ws + 38535168);          // [7][16][3][128][192] f32 (33,030,144)
  u16* vkb = (u16*)(ws + 71565312);                 // [16][384][192] bf16 (2,359,296)
  u16* yt = (u16*)(ws + szY);                       // [B][N][A] bf16
  u16* skq = (u16*)(ws + 2 * szY);                  // [B][N][384] bf16 (38,535,168)
  char* ws2 = ws + 2 * szY + 38535168;
  float* kfp = (float*)(ws2);                       // [7][16][192] f32 (86,016)
  float* zinv = (float*)(ws2 + 86016);              // [B][N] f32 (200,704)
  u16* pwb = (u16*)(ws2 + 86016 + 200704);          // [768][192] bf16 (294,912)
  u16* gwb = (u16*)(ws2 + 86016 + 200704 + 294912); // [384][768] bf16 (589,824)
  u16* owb = (u16*)(ws2 + 86016 + 200704 + 294912 + 589824);  // [192][384] (147,456)

  k_prep<<<dim3(252), 256, 0, stream>>>(pw, gw, ow, pwb, gwb, owb);
  k_proj<<<dim3(49, 3, 16), 256, 0, stream>>>(x, pwb, pb, y0t);
  k_dwc<<<dim3(2688), 256, 0, stream>>>(y0t, cw, cb, yt, skq);
  k_kfmean<<<dim3(7, 3, 16), 256, 0, stream>>>(skq, kfp);
  k_z<<<dim3(13, 16), 256, 0, stream>>>(skq, kfp, zinv);
  k_vk<<<dim3(336), 256, 0, stream>>>(skq, yt, vkpart);
  k_vkred<<<dim3(576), 256, 0, stream>>>(vkpart, vkb);
  k_gateattn<<<dim3(1568), 256, 0, stream>>>(yt, skq, zinv, vkb, gwb, gb, attnt);
  k_rmsfinal<<<dim3(98, 16), 256, 0, stream>>>(yt, anw, svw, attnt);
  k_out<<<dim3(49, 16), 256, 0, stream>>>(attnt, owb, ob, out);
}

// Round 4
// 315.635 us; speedup vs baseline: 4.8693x; 1.0027x over previous
//
#include <hip/hip_runtime.h>
#include <hip/hip_bf16.h>

typedef unsigned short u16;
typedef __attribute__((ext_vector_type(8))) short bf16x8;
typedef __attribute__((ext_vector_type(4))) float f32x4;

constexpr int B_ = 16, C_ = 192, H_ = 56, W_ = 56;
constexpr int N_ = H_ * W_;   // 3136
constexpr int A_ = 768;       // attn_dim
constexpr int Dq = 192;       // d_qk
constexpr int Vd = 384;       // d_v
constexpr float EPSf = 1e-6f;

union U8 { bf16x8 v; u16 s[8]; unsigned u[4]; };

__device__ __forceinline__ float bits2f(u16 u) {
  return __uint_as_float(((unsigned)u) << 16);
}
__device__ __forceinline__ u16 f2bits(float f) {
  __hip_bfloat16 h = __float2bfloat16(f);
  u16 u;
  __builtin_memcpy(&u, &h, sizeof(u));
  return u;
}
__device__ __forceinline__ float silu_f(float v) { return v / (1.0f + __expf(-v)); }
__device__ __forceinline__ float sigm_f(float v) { return 1.0f / (1.0f + __expf(-v)); }

__device__ __forceinline__ f32x4 MFMA(bf16x8 a, bf16x8 b, f32x4 c) {
  return __builtin_amdgcn_mfma_f32_16x16x32_bf16(a, b, c, 0, 0, 0);
}

// ============ K0: weight pre-convert f32 -> bf16 (pw, gw, ow)
__global__ __launch_bounds__(256) void k_prep(const float* __restrict__ pw,
                                              const float* __restrict__ gw,
                                              const float* __restrict__ ow,
                                              u16* __restrict__ pwb,
                                              u16* __restrict__ gwb,
                                              u16* __restrict__ owb) {
  const int bid = blockIdx.x;
  const size_t base = ((size_t)bid * 256 + threadIdx.x) * 8;
  const float* src;
  u16* dst;
  size_t off;
  if (bid < 72) { src = pw; dst = pwb; off = base; }
  else if (bid < 216) { src = gw; dst = gwb; off = base - 147456; }
  else { src = ow; dst = owb; off = base - 442368; }
  float4 v0 = *(const float4*)&src[off];
  float4 v1 = *(const float4*)&src[off + 4];
  U8 r;
  r.s[0] = f2bits(v0.x); r.s[1] = f2bits(v0.y); r.s[2] = f2bits(v0.z); r.s[3] = f2bits(v0.w);
  r.s[4] = f2bits(v1.x); r.s[5] = f2bits(v1.y); r.s[6] = f2bits(v1.z); r.s[7] = f2bits(v1.w);
  *(bf16x8*)&dst[off] = r.v;
}

// ============ K1: proj GEMM  y0t[b][n][o] = sum_c pw[o,c]*x[b,c,n] + pb[o]
// block: 256 o x 64 n. Xt persistent (K=192), Wa swizzled per-ks.
__global__ __launch_bounds__(256) void k_proj(const float* __restrict__ x,
                                              const u16* __restrict__ pwb,
                                              const float* __restrict__ pb,
                                              u16* __restrict__ y0t) {
  const int n0 = blockIdx.x * 64;
  const int oy = blockIdx.y;  // 0..2
  const int b = blockIdx.z;
  __shared__ u16 Xt[64][200];  // [n][c], 400B stride (16B mult)
  __shared__ u16 Wa[256][32];  // [o][k32], swizzled 16B blocks
  const int t = threadIdx.x;
  const int lane = t & 63, wid = t >> 6;
  const int fr = lane & 15, fg = lane >> 4;

  // stage Xt: x[b][c][n] -> Xt[n][c]
  {
    const int p = t & 31, co = t >> 5;
    const float* xb = x + (size_t)b * C_ * N_ + n0 + 2 * p;
#pragma unroll
    for (int rnd = 0; rnd < 3; ++rnd) {
      const int c0 = rnd * 64 + co * 8;
      float2 v[8];
#pragma unroll
      for (int i = 0; i < 8; ++i) v[i] = *(const float2*)&xb[(size_t)(c0 + i) * N_];
      U8 r0, r1;
#pragma unroll
      for (int i = 0; i < 8; ++i) { r0.s[i] = f2bits(v[i].x); r1.s[i] = f2bits(v[i].y); }
      *(bf16x8*)&Xt[2 * p][c0] = r0.v;
      *(bf16x8*)&Xt[2 * p + 1][c0] = r1.v;
    }
  }

  f32x4 acc[4][4];
#pragma unroll
  for (int mi = 0; mi < 4; ++mi)
#pragma unroll
    for (int ni = 0; ni < 4; ++ni) acc[mi][ni] = (f32x4){0.f, 0.f, 0.f, 0.f};

  const int orow_c = t >> 2, oct_c = t & 3;
  for (int ks = 0; ks < 6; ++ks) {
    __syncthreads();  // Wa overwrite guard (also covers Xt on first iter)
#pragma unroll
    for (int jj = 0; jj < 4; ++jj) {
      const int orow = orow_c + 64 * jj;
      const int sw = (orow >> 1) & 3;
      bf16x8 v = *(const bf16x8*)&pwb[(size_t)(oy * 256 + orow) * C_ + ks * 32 + oct_c * 8];
      *(bf16x8*)&Wa[orow][(oct_c ^ sw) * 8] = v;
    }
    __syncthreads();
    bf16x8 bfrag[4];
#pragma unroll
    for (int ni = 0; ni < 4; ++ni)
      bfrag[ni] = *(const bf16x8*)&Xt[ni * 16 + fr][ks * 32 + fg * 8];
#pragma unroll
    for (int mi = 0; mi < 4; ++mi) {
      const int ar = wid * 64 + mi * 16 + fr;
      bf16x8 a = *(const bf16x8*)&Wa[ar][(fg ^ ((ar >> 1) & 3)) * 8];
#pragma unroll
      for (int ni = 0; ni < 4; ++ni) acc[mi][ni] = MFMA(a, bfrag[ni], acc[mi][ni]);
    }
  }
#pragma unroll
  for (int mi = 0; mi < 4; ++mi) {
    const int o4 = oy * 256 + wid * 64 + mi * 16 + fg * 4;
    const float b0 = pb[o4], b1 = pb[o4 + 1], b2 = pb[o4 + 2], b3 = pb[o4 + 3];
#pragma unroll
    for (int ni = 0; ni < 4; ++ni) {
      const int n = n0 + ni * 16 + fr;
      ushort4 pk;
      pk.x = f2bits(acc[mi][ni][0] + b0);
      pk.y = f2bits(acc[mi][ni][1] + b1);
      pk.z = f2bits(acc[mi][ni][2] + b2);
      pk.w = f2bits(acc[mi][ni][3] + b3);
      *(ushort4*)&y0t[((size_t)b * N_ + n) * A_ + o4] = pk;
    }
  }
}

// ============ K2: depthwise 3x3 + bias + residual; also writes skq = silu(y[:, :384])
__global__ __launch_bounds__(256) void k_dwc(const u16* __restrict__ y0t,
                                             const float* __restrict__ cw,
                                             const float* __restrict__ cb,
                                             u16* __restrict__ yt,
                                             u16* __restrict__ skq) {
  const int pid = blockIdx.x;
  const int L = (pid & 7) * 336 + (pid >> 3);  // 2688 = 8*336
  const int h = L % 56, at = (L / 56) % 3, b = L / 168;
  const int t = threadIdx.x;
  const int a = at * 256 + (t & 31) * 8;
  const int wl = t >> 5;
  float w9[9][8];
  float bias[8];
#pragma unroll
  for (int j = 0; j < 8; ++j) {
    bias[j] = cb[a + j];
#pragma unroll
    for (int k = 0; k < 9; ++k) w9[k][j] = cw[(a + j) * 9 + k];
  }
  const u16* src = y0t + (size_t)b * N_ * A_ + a;
  u16* dst = yt + (size_t)b * N_ * A_ + a;
  const bool hok0 = h > 0, hok2 = h < 55;
  for (int wc = 0; wc < 7; ++wc) {
    const int w = wc * 8 + wl;
    const bool wok0 = w > 0, wok2 = w < 55;
    U8 nb[9];
#pragma unroll
    for (int dh = -1; dh <= 1; ++dh) {
      const bool hok = (dh == -1) ? hok0 : ((dh == 1) ? hok2 : true);
#pragma unroll
      for (int dw = -1; dw <= 1; ++dw) {
        const int k = (dh + 1) * 3 + (dw + 1);
        const bool ok = hok && ((dw == -1) ? wok0 : ((dw == 1) ? wok2 : true));
        if (ok)
          nb[k].v = *(const bf16x8*)&src[(size_t)((h + dh) * 56 + (w + dw)) * A_];
        else
          nb[k].u[0] = nb[k].u[1] = nb[k].u[2] = nb[k].u[3] = 0u;
      }
    }
    U8 o;
    float sv[8];
#pragma unroll
    for (int j = 0; j < 8; ++j) {
      float s = bias[j] + bits2f(nb[4].s[j]);
#pragma unroll
      for (int k = 0; k < 9; ++k) s = fmaf(w9[k][j], bits2f(nb[k].s[j]), s);
      sv[j] = s;
      o.s[j] = f2bits(s);
    }
    *(bf16x8*)&dst[(size_t)(h * 56 + w) * A_] = o.v;
    if (a < 384) {
      U8 q;
#pragma unroll
      for (int j = 0; j < 8; ++j) q.s[j] = f2bits(silu_f(sv[j]));
      *(bf16x8*)&skq[((size_t)b * N_ + h * 56 + w) * 384 + a] = q.v;
    }
  }
}

// ============ K3: kfmean partials from skq k-part (pre-silu'd)
__global__ __launch_bounds__(256) void k_kfmean(const u16* __restrict__ skq,
                                                float* __restrict__ kfp) {
  const int ns = blockIdx.x, dc = blockIdx.y, b = blockIdx.z;
  const int t = threadIdx.x;
  const int dq = t & 15, nw = t >> 4;
  const u16* p = skq + ((size_t)b * N_ + ns * 448 + nw) * 384 + 192 + dc * 64 + dq * 4;
  float s0 = 0, s1 = 0, s2 = 0, s3 = 0;
#pragma unroll 4
  for (int i = 0; i < 28; ++i) {
    ushort4 u = *(const ushort4*)&p[(size_t)i * 16 * 384];
    s0 += bits2f(u.x);
    s1 += bits2f(u.y);
    s2 += bits2f(u.z);
    s3 += bits2f(u.w);
  }
  __shared__ float red[16][65];
  red[nw][dq * 4 + 0] = s0;
  red[nw][dq * 4 + 1] = s1;
  red[nw][dq * 4 + 2] = s2;
  red[nw][dq * 4 + 3] = s3;
  __syncthreads();
  if (t < 64) {
    float s = 0;
#pragma unroll
    for (int i = 0; i < 16; ++i) s += red[i][t];
    kfp[((size_t)ns * B_ + b) * Dq + dc * 64 + t] = s * (1.0f / (float)N_);
  }
}

// ============ K4: zinv[b][n] = 1/(sum_d kfm[d]*qf[n,d] + EPS)  (qf from skq)
__global__ __launch_bounds__(256) void k_z(const u16* __restrict__ skq,
                                           const float* __restrict__ kfp,
                                           float* __restrict__ zinv) {
  const int b = blockIdx.y;
  const int n = blockIdx.x * 256 + threadIdx.x;
  __shared__ float kf[192];
  if (threadIdx.x < 192) {
    float s = 0;
#pragma unroll
    for (int ns = 0; ns < 7; ++ns) s += kfp[((size_t)ns * B_ + b) * Dq + threadIdx.x];
    kf[threadIdx.x] = s;
  }
  __syncthreads();
  if (n < N_) {
    const u16* p = skq + ((size_t)b * N_ + n) * 384;
    float z = 0;
#pragma unroll
    for (int j = 0; j < 24; ++j) {
      U8 u;
      u.v = *(const bf16x8*)&p[j * 8];
#pragma unroll
      for (int i = 0; i < 8; ++i) z = fmaf(kf[j * 8 + i], bits2f(u.s[i]), z);
    }
    zinv[(size_t)b * N_ + n] = 1.0f / (z + EPSf);
  }
}

// ============ K5: vk GEMM, split-K over N (7 chunks), 128v x 192d tiles.
// LDS: unified 320-row transposed tile, XOR-swizzled, partials in f32.
__global__ __launch_bounds__(256) void k_vk(const u16* __restrict__ skq,
                                            const u16* __restrict__ yt,
                                            float* __restrict__ vkpart) {
  const int pid = blockIdx.x;  // 336 = 8*42
  const int L = (pid & 7) * 42 + (pid >> 3);
  const int ns = L % 7;
  const int vblk = (L / 7) % 3;
  const int b = L / 21;
  const int t = threadIdx.x;
  const int lane = t & 63, wid = t >> 6;
  const int fr = lane & 15, fg = lane >> 4;
  const int vbase = (wid >> 1) * 64, dbase = (wid & 1) * 96;

  __shared__ u16 T[320 * 64];  // rows 0..191: K(d); rows 192..319: V
  unsigned* T32 = (unsigned*)T;

  const int oct0 = t & 7;
  const int pair = (t >> 3) & 31;
  const int nb0 = ns * 448;

  U8 pre[5][2];
  auto load_pre = [&](int n0) {
    const int n = nb0 + n0 + pair * 2;
#pragma unroll
    for (int j = 0; j < 5; ++j) {
      const int oct = oct0 + 8 * j;
      const u16* srcp;
      size_t stride;
      if (j < 3) {
        srcp = skq + ((size_t)b * N_ + n) * 384 + 192 + oct * 8;
        stride = 384;
      } else {
        srcp = yt + ((size_t)b * N_ + n) * A_ + 384 + vblk * 128 + (oct - 24) * 8;
        stride = A_;
      }
      pre[j][0].v = *(const bf16x8*)srcp;
      pre[j][1].v = *(const bf16x8*)(srcp + stride);
    }
  };

  f32x4 acc[4][6];
#pragma unroll
  for (int mi = 0; mi < 4; ++mi)
#pragma unroll
    for (int ni = 0; ni < 6; ++ni) acc[mi][ni] = (f32x4){0.f, 0.f, 0.f, 0.f};

  load_pre(0);
  for (int s = 0; s < 7; ++s) {
    __syncthreads();  // prior MFMA done reading T
#pragma unroll
    for (int j = 0; j < 5; ++j) {
      const int rowb = (oct0 + 8 * j) * 8;
#pragma unroll
      for (int i = 0; i < 8; ++i) {
        const int row = rowb + i;
        const int sw = (row & 7) ^ ((row >> 3) & 7);
        const unsigned val =
            ((unsigned)pre[j][0].s[i] & 0xffffu) | (((unsigned)pre[j][1].s[i]) << 16);
        T32[row * 32 + (pair ^ (sw << 2))] = val;
      }
    }
    __syncthreads();
    if (s < 6) load_pre((s + 1) * 64);  // prefetch next step under MFMA
#pragma unroll
    for (int kf2 = 0; kf2 < 2; ++kf2) {
      bf16x8 bfrag[6];
#pragma unroll
      for (int ni = 0; ni < 6; ++ni) {
        const int row = dbase + ni * 16 + fr;
        const int sw = (row & 7) ^ ((row >> 3) & 7);
        bfrag[ni] = *(const bf16x8*)&T[row * 64 + ((kf2 * 32 + fg * 8) ^ (sw << 3))];
      }
#pragma unroll
      for (int mi = 0; mi < 4; ++mi) {
        const int row = 192 + vbase + mi * 16 + fr;
        const int sw = (row & 7) ^ ((row >> 3) & 7);
        bf16x8 a = *(const bf16x8*)&T[row * 64 + ((kf2 * 32 + fg * 8) ^ (sw << 3))];
#pragma unroll
        for (int ni = 0; ni < 6; ++ni) acc[mi][ni] = MFMA(a, bfrag[ni], acc[mi][ni]);
      }
    }
  }
  float* base = vkpart + (((size_t)ns * 16 + b) * 3 + vblk) * (128 * 192);
#pragma unroll
  for (int mi = 0; mi < 4; ++mi)
#pragma unroll
    for (int ni = 0; ni < 6; ++ni) {
      const int v = vbase + mi * 16 + fg * 4;
      const int d = dbase + ni * 16 + fr;
      float* o = base + (size_t)v * 192 + d;
      o[0] = acc[mi][ni][0];
      o[192] = acc[mi][ni][1];
      o[384] = acc[mi][ni][2];
      o[576] = acc[mi][ni][3];
    }
}

// ============ K5b: reduce 7 partials -> vkb bf16 [b][384][192] (with 1/N)
__global__ __launch_bounds__(256) void k_vkred(const float* __restrict__ vkpart,
                                               u16* __restrict__ vkb) {
  const size_t e = ((size_t)blockIdx.x * 256 + threadIdx.x) * 8;
  constexpr size_t NSSTRIDE = (size_t)16 * 3 * 128 * 192;
  float4 s0 = {0, 0, 0, 0}, s1 = {0, 0, 0, 0};
#pragma unroll
  for (int ns = 0; ns < 7; ++ns) {
    float4 a0 = *(const float4*)&vkpart[ns * NSSTRIDE + e];
    float4 a1 = *(const float4*)&vkpart[ns * NSSTRIDE + e + 4];
    s0.x += a0.x; s0.y += a0.y; s0.z += a0.z; s0.w += a0.w;
    s1.x += a1.x; s1.y += a1.y; s1.z += a1.z; s1.w += a1.w;
  }
  const float sc = 1.0f / (float)N_;
  U8 r;
  r.s[0] = f2bits(s0.x * sc); r.s[1] = f2bits(s0.y * sc);
  r.s[2] = f2bits(s0.z * sc); r.s[3] = f2bits(s0.w * sc);
  r.s[4] = f2bits(s1.x * sc); r.s[5] = f2bits(s1.y * sc);
  r.s[6] = f2bits(s1.z * sc); r.s[7] = f2bits(s1.w * sc);
  *(bf16x8*)&vkb[e] = r.v;
}

// ============ K6: fused attn0 (vkb@qf /z) and gate (sigmoid(gwb@xs+gb)); writes attnt[n][v]
__global__ __launch_bounds__(256, 3) void k_gateattn(const u16* __restrict__ yt,
                                                     const u16* __restrict__ skq,
                                                     const float* __restrict__ zinv,
                                                     const u16* __restrict__ vkb,
                                                     const u16* __restrict__ gwb,
                                                     const float* __restrict__ gb,
                                                     u16* __restrict__ attnt) {
  const int pid = blockIdx.x;
  const int L = (pid & 7) * 196 + (pid >> 3);  // 1568 = 8*196
  const int vh = L & 1;
  const int n0 = ((L >> 1) % 49) * 64;
  const int b = L / 98;
  const int t = threadIdx.x;
  const int lane = t & 63, wid = t >> 6, wm = wid >> 1, wn = wid & 1;
  const int fr = lane & 15, fg = lane >> 4;
  __shared__ u16 Wa[192][40];
  __shared__ u16 Xt[64][40];
  __shared__ float zl[64];
  if (t < 64) zl[t] = zinv[(size_t)b * N_ + n0 + t];
  const u16* yb = yt + ((size_t)b * N_ + n0) * A_;
  const u16* qb = skq + ((size_t)b * N_ + n0) * 384;

  f32x4 acc[6][2];
#pragma unroll
  for (int mi = 0; mi < 6; ++mi)
#pragma unroll
    for (int ni = 0; ni < 2; ++ni) acc[mi][ni] = (f32x4){0.f, 0.f, 0.f, 0.f};

  // ---- attn0 = vkb @ qf, K = 192
  for (int ks = 0; ks < 6; ++ks) {
    {
      const int o = t >> 2, cs = t & 3;
#pragma unroll
      for (int rr = 0; rr < 3; ++rr) {
        const int v = rr * 64 + o;
        *(bf16x8*)&Wa[v][cs * 8] =
            *(const bf16x8*)&vkb[((size_t)(vh * 192 + v) + 0) * 0 +
                                 ((size_t)b * Vd + vh * 192 + v) * 192 + ks * 32 + cs * 8];
      }
    }
    {
      const int n = t >> 2, aq = t & 3;
      *(bf16x8*)&Xt[n][aq * 8] = *(const bf16x8*)&qb[(size_t)n * 384 + ks * 32 + aq * 8];
    }
    __syncthreads();
    bf16x8 bfr[2];
#pragma unroll
    for (int ni = 0; ni < 2; ++ni) bfr[ni] = *(const bf16x8*)&Xt[wn * 32 + ni * 16 + fr][fg * 8];
#pragma unroll
    for (int mi = 0; mi < 6; ++mi) {
      bf16x8 a = *(const bf16x8*)&Wa[wm * 96 + mi * 16 + fr][fg * 8];
      acc[mi][0] = MFMA(a, bfr[0], acc[mi][0]);
      acc[mi][1] = MFMA(a, bfr[1], acc[mi][1]);
    }
    __syncthreads();
  }

  // apply 1/z and stash as packed bf16 in registers
  uint2 pp[6][2];
#pragma unroll
  for (int mi = 0; mi < 6; ++mi)
#pragma unroll
    for (int ni = 0; ni < 2; ++ni) {
      const float z = zl[wn * 32 + ni * 16 + fr];
      unsigned a0 = ((unsigned)f2bits(acc[mi][ni][0] * z) & 0xffffu) |
                    (((unsigned)f2bits(acc[mi][ni][1] * z) & 0xffffu) << 16);
      unsigned a1 = ((unsigned)f2bits(acc[mi][ni][2] * z) & 0xffffu) |
                    (((unsigned)f2bits(acc[mi][ni][3] * z) & 0xffffu) << 16);
      pp[mi][ni] = make_uint2(a0, a1);
      acc[mi][ni] = (f32x4){0.f, 0.f, 0.f, 0.f};
    }

  // ---- gate = gwb @ xs, K = 768
  for (int ks = 0; ks < 24; ++ks) {
    {
      const int o = t >> 2, cs = t & 3;
#pragma unroll
      for (int rr = 0; rr < 3; ++rr) {
        const int v = rr * 64 + o;
        *(bf16x8*)&Wa[v][cs * 8] =
            *(const bf16x8*)&gwb[(size_t)(vh * 192 + v) * A_ + ks * 32 + cs * 8];
      }
    }
    {
      const int n = t >> 2, aq = t & 3;
      *(bf16x8*)&Xt[n][aq * 8] = *(const bf16x8*)&yb[(size_t)n * A_ + ks * 32 + aq * 8];
    }
    __syncthreads();
    bf16x8 bfr[2];
#pragma unroll
    for (int ni = 0; ni < 2; ++ni) bfr[ni] = *(const bf16x8*)&Xt[wn * 32 + ni * 16 + fr][fg * 8];
#pragma unroll
    for (int mi = 0; mi < 6; ++mi) {
      bf16x8 a = *(const bf16x8*)&Wa[wm * 96 + mi * 16 + fr][fg * 8];
      acc[mi][0] = MFMA(a, bfr[0], acc[mi][0]);
      acc[mi][1] = MFMA(a, bfr[1], acc[mi][1]);
    }
    __syncthreads();
  }

  // ---- combine and write attnt[n][v]
#pragma unroll
  for (int mi = 0; mi < 6; ++mi) {
    const int vb = vh * 192 + wm * 96 + mi * 16 + fg * 4;
    const float g0 = gb[vb], g1 = gb[vb + 1], g2 = gb[vb + 2], g3 = gb[vb + 3];
#pragma unroll
    for (int ni = 0; ni < 2; ++ni) {
      const int n = n0 + wn * 32 + ni * 16 + fr;
      const uint2 p = pp[mi][ni];
      const float pv0 = bits2f((u16)(p.x & 0xffffu)), pv1 = bits2f((u16)(p.x >> 16));
      const float pv2 = bits2f((u16)(p.y & 0xffffu)), pv3 = bits2f((u16)(p.y >> 16));
      ushort4 o;
      o.x = f2bits(pv0 * sigm_f(acc[mi][ni][0] + g0));
      o.y = f2bits(pv1 * sigm_f(acc[mi][ni][1] + g1));
      o.z = f2bits(pv2 * sigm_f(acc[mi][ni][2] + g2));
      o.w = f2bits(pv3 * sigm_f(acc[mi][ni][3] + g3));
      *(ushort4*)&attnt[((size_t)b * N_ + n) * Vd + vb] = o;
    }
  }
}

// ============ K7: rms over v (384) per n, final combine (in place on attnt)
__global__ __launch_bounds__(256) void k_rmsfinal(const u16* __restrict__ yt,
                                                  const float* __restrict__ anw,
                                                  const float* __restrict__ svw,
                                                  u16* __restrict__ attnt) {
  const int b = blockIdx.y;
  const int n0 = blockIdx.x * 32;
  const int t = threadIdx.x;
  __shared__ float anws[384], svws[384];
  for (int i = t; i < 384; i += 256) {
    anws[i] = anw[i];
    svws[i] = svw[i];
  }
  __syncthreads();
  const int n = n0 + (t >> 3);
  const int vs = (t & 7) * 8;
  u16* ap = attnt + ((size_t)b * N_ + n) * Vd;
  U8 av[6];
  float ss = 0.f;
#pragma unroll
  for (int j = 0; j < 6; ++j) {
    av[j].v = *(const bf16x8*)&ap[vs + j * 64];
#pragma unroll
    for (int i = 0; i < 8; ++i) {
      const float f = bits2f(av[j].s[i]);
      ss = fmaf(f, f, ss);
    }
  }
  ss += __shfl_xor(ss, 1);
  ss += __shfl_xor(ss, 2);
  ss += __shfl_xor(ss, 4);
  const float rinv = rsqrtf(ss * (1.0f / (float)Vd) + EPSf);
  const u16* vp = yt + ((size_t)b * N_ + n) * A_ + 2 * Dq;
#pragma unroll
  for (int j = 0; j < 6; ++j) {
    U8 vv, o;
    vv.v = *(const bf16x8*)&vp[vs + j * 64];
#pragma unroll
    for (int i = 0; i < 8; ++i) {
      const int v = vs + j * 64 + i;
      const float val = bits2f(av[j].s[i]) * rinv * anws[v] + bits2f(vv.s[i]) * svws[v];
      o.s[i] = f2bits(val);
    }
    *(bf16x8*)&ap[vs + j * 64] = o.v;
  }
}

// ============ K8: out GEMM  out[b][c][n] = sum_v ow[c,v]*attnt[n][v] + ob[c]
__global__ __launch_bounds__(256, 2) void k_out(const u16* __restrict__ attnt,
                                                const u16* __restrict__ owb,
                                                const float* __restrict__ ob,
                                                float* __restrict__ out) {
  const int n0 = blockIdx.x * 64;
  const int b = blockIdx.y;
  __shared__ u16 Xt[64][392];
  __shared__ u16 Wa[64][40];
  const int t = threadIdx.x;
  const int lane = t & 63, wid = t >> 6, wm = wid >> 1, wn = wid & 1;
  const int fr = lane & 15, fg = lane >> 4;
  {
    const int n = t >> 2, aq = t & 3;
    const u16* src = attnt + ((size_t)b * N_ + n0 + n) * Vd + aq * 8;
#pragma unroll
    for (int vr = 0; vr < 12; ++vr)
      *(bf16x8*)&Xt[n][vr * 32 + aq * 8] = *(const bf16x8*)&src[vr * 32];
  }
  f32x4 acc[2][2];
  for (int cb = 0; cb < 3; ++cb) {
#pragma unroll
    for (int mi = 0; mi < 2; ++mi)
#pragma unroll
      for (int ni = 0; ni < 2; ++ni) acc[mi][ni] = (f32x4){0.f, 0.f, 0.f, 0.f};
    for (int ks = 0; ks < 12; ++ks) {
      {
        const int o = t >> 2, cs = t & 3;
        *(bf16x8*)&Wa[o][cs * 8] =
            *(const bf16x8*)&owb[(size_t)(cb * 64 + o) * Vd + ks * 32 + cs * 8];
      }
      __syncthreads();
      bf16x8 a0 = *(const bf16x8*)&Wa[wm * 32 + fr][fg * 8];
      bf16x8 a1 = *(const bf16x8*)&Wa[wm * 32 + 16 + fr][fg * 8];
      bf16x8 b0 = *(const bf16x8*)&Xt[wn * 32 + fr][ks * 32 + fg * 8];
      bf16x8 b1 = *(const bf16x8*)&Xt[wn * 32 + 16 + fr][ks * 32 + fg * 8];
      acc[0][0] = MFMA(a0, b0, acc[0][0]);
      acc[0][1] = MFMA(a0, b1, acc[0][1]);
      acc[1][0] = MFMA(a1, b0, acc[1][0]);
      acc[1][1] = MFMA(a1, b1, acc[1][1]);
      __syncthreads();
    }
#pragma unroll
    for (int mi = 0; mi < 2; ++mi) {
      const int c = cb * 64 + wm * 32 + mi * 16 + fg * 4;
      const float b0 = ob[c], b1 = ob[c + 1], b2 = ob[c + 2], b3 = ob[c + 3];
#pragma unroll
      for (int ni = 0; ni < 2; ++ni) {
        const int n = n0 + wn * 32 + ni * 16 + fr;
        float* o = out + ((size_t)b * C_ + c) * N_ + n;
        o[0 * N_] = acc[mi][ni][0] + b0;
        o[1 * N_] = acc[mi][ni][1] + b1;
        o[2 * N_] = acc[mi][ni][2] + b2;
        o[3 * N_] = acc[mi][ni][3] + b3;
      }
    }
  }
}

extern "C" void kernel_launch(void* const* d_in, const int* in_sizes, int n_in,
                              void* d_out, int out_size, void* d_ws, size_t ws_size,
                              hipStream_t stream) {
  (void)in_sizes; (void)n_in; (void)out_size; (void)ws_size;
  const float* x = (const float*)d_in[0];
  const float* pw = (const float*)d_in[1];
  const float* pb = (const float*)d_in[2];
  const float* cw = (const float*)d_in[3];
  const float* cb = (const float*)d_in[4];
  const float* gw = (const float*)d_in[5];
  const float* gb = (const float*)d_in[6];
  const float* anw = (const float*)d_in[7];
  const float* svw = (const float*)d_in[8];
  const float* ow = (const float*)d_in[9];
  const float* ob = (const float*)d_in[10];
  float* out = (float*)d_out;

  char* ws = (char*)d_ws;
  const size_t szY = (size_t)B_ * N_ * A_ * 2;  // 77,070,336
  // Region R0 (0..szY): y0t until k_dwc; then attnt / vkpart / vkb.
  u16* y0t = (u16*)(ws);
  u16* attnt = (u16*)(ws);                          // [B][N][384] bf16 (38,535,168)
  float* vkpart = (float*)(ws + 38535168);          // [7][16][3][128][192] f32 (33,030,144)
  u16* vkb = (u16*)(ws + 71565312);                 // [16][384][192] bf16 (2,359,296)
  u16* yt = (u16*)(ws + szY);                       // [B][N][A] bf16
  u16* skq = (u16*)(ws + 2 * szY);                  // [B][N][384] bf16 (38,535,168)
  char* ws2 = ws + 2 * szY + 38535168;
  float* kfp = (float*)(ws2);                       // [7][16][192] f32 (86,016)
  float* zinv = (float*)(ws2 + 86016);              // [B][N] f32 (200,704)
  u16* pwb = (u16*)(ws2 + 86016 + 200704);          // [768][192] bf16 (294,912)
  u16* gwb = (u16*)(ws2 + 86016 + 200704 + 294912); // [384][768] bf16 (589,824)
  u16* owb = (u16*)(ws2 + 86016 + 200704 + 294912 + 589824);  // [192][384] (147,456)

  k_prep<<<dim3(252), 256, 0, stream>>>(pw, gw, ow, pwb, gwb, owb);
  k_proj<<<dim3(49, 3, 16), 256, 0, stream>>>(x, pwb, pb, y0t);
  k_dwc<<<dim3(2688), 256, 0, stream>>>(y0t, cw, cb, yt, skq);
  k_kfmean<<<dim3(7, 3, 16), 256, 0, stream>>>(skq, kfp);
  k_z<<<dim3(13, 16), 256, 0, stream>>>(skq, kfp, zinv);
  k_vk<<<dim3(336), 256, 0, stream>>>(skq, yt, vkpart);
  k_vkred<<<dim3(576), 256, 0, stream>>>(vkpart, vkb);
  k_gateattn<<<dim3(1568), 256, 0, stream>>>(yt, skq, zinv, vkb, gwb, gb, attnt);
  k_rmsfinal<<<dim3(98, 16), 256, 0, stream>>>(yt, anw, svw, attnt);
  k_out<<<dim3(49, 16), 256, 0, stream>>>(attnt, owb, ob, out);
}

// Round 5
// 272.600 us; speedup vs baseline: 5.6380x; 1.1579x over previous
//
#include <hip/hip_runtime.h>
#include <hip/hip_bf16.h>

typedef unsigned short u16;
typedef __attribute__((ext_vector_type(8))) short bf16x8;
typedef __attribute__((ext_vector_type(4))) float f32x4;

constexpr int B_ = 16, C_ = 192, H_ = 56, W_ = 56;
constexpr int N_ = H_ * W_;   // 3136
constexpr int A_ = 768;       // attn_dim
constexpr int Dq = 192;       // d_qk
constexpr int Vd = 384;       // d_v
constexpr float EPSf = 1e-6f;

union U8 { bf16x8 v; u16 s[8]; unsigned u[4]; };

__device__ __forceinline__ float bits2f(u16 u) {
  return __uint_as_float(((unsigned)u) << 16);
}
__device__ __forceinline__ u16 f2bits(float f) {
  __hip_bfloat16 h = __float2bfloat16(f);
  u16 u;
  __builtin_memcpy(&u, &h, sizeof(u));
  return u;
}
__device__ __forceinline__ float silu_f(float v) { return v / (1.0f + __expf(-v)); }
__device__ __forceinline__ float sigm_f(float v) { return 1.0f / (1.0f + __expf(-v)); }

__device__ __forceinline__ f32x4 MFMA(bf16x8 a, bf16x8 b, f32x4 c) {
  return __builtin_amdgcn_mfma_f32_16x16x32_bf16(a, b, c, 0, 0, 0);
}

// ============ K0: weight pre-convert f32 -> bf16 (pw, gw, ow)
__global__ __launch_bounds__(256) void k_prep(const float* __restrict__ pw,
                                              const float* __restrict__ gw,
                                              const float* __restrict__ ow,
                                              u16* __restrict__ pwb,
                                              u16* __restrict__ gwb,
                                              u16* __restrict__ owb) {
  const int bid = blockIdx.x;
  const size_t base = ((size_t)bid * 256 + threadIdx.x) * 8;
  const float* src;
  u16* dst;
  size_t off;
  if (bid < 72) { src = pw; dst = pwb; off = base; }
  else if (bid < 216) { src = gw; dst = gwb; off = base - 147456; }
  else { src = ow; dst = owb; off = base - 442368; }
  float4 v0 = *(const float4*)&src[off];
  float4 v1 = *(const float4*)&src[off + 4];
  U8 r;
  r.s[0] = f2bits(v0.x); r.s[1] = f2bits(v0.y); r.s[2] = f2bits(v0.z); r.s[3] = f2bits(v0.w);
  r.s[4] = f2bits(v1.x); r.s[5] = f2bits(v1.y); r.s[6] = f2bits(v1.z); r.s[7] = f2bits(v1.w);
  *(bf16x8*)&dst[off] = r.v;
}

// ============ K1: proj GEMM  y0t[b][n][o] = sum_c pw[o,c]*x[b,c,n] + pb[o]
// block: 256 o x 64 n. Xt persistent (K=192), Wa swizzled per-ks, reg-prefetch.
__global__ __launch_bounds__(256) void k_proj(const float* __restrict__ x,
                                              const u16* __restrict__ pwb,
                                              const float* __restrict__ pb,
                                              u16* __restrict__ y0t) {
  const int n0 = blockIdx.x * 64;
  const int oy = blockIdx.y;  // 0..2
  const int b = blockIdx.z;
  __shared__ u16 Xt[64][200];  // [n][c], 400B stride
  __shared__ u16 Wa[256][32];  // [o][k32], swizzled 16B blocks
  const int t = threadIdx.x;
  const int lane = t & 63, wid = t >> 6;
  const int fr = lane & 15, fg = lane >> 4;

  // stage Xt: x[b][c][n] -> Xt[n][c]
  {
    const int p = t & 31, co = t >> 5;
    const float* xb = x + (size_t)b * C_ * N_ + n0 + 2 * p;
#pragma unroll
    for (int rnd = 0; rnd < 3; ++rnd) {
      const int c0 = rnd * 64 + co * 8;
      float2 v[8];
#pragma unroll
      for (int i = 0; i < 8; ++i) v[i] = *(const float2*)&xb[(size_t)(c0 + i) * N_];
      U8 r0, r1;
#pragma unroll
      for (int i = 0; i < 8; ++i) { r0.s[i] = f2bits(v[i].x); r1.s[i] = f2bits(v[i].y); }
      *(bf16x8*)&Xt[2 * p][c0] = r0.v;
      *(bf16x8*)&Xt[2 * p + 1][c0] = r1.v;
    }
  }

  f32x4 acc[4][4];
#pragma unroll
  for (int mi = 0; mi < 4; ++mi)
#pragma unroll
    for (int ni = 0; ni < 4; ++ni) acc[mi][ni] = (f32x4){0.f, 0.f, 0.f, 0.f};

  const int orow_c = t >> 2, oct_c = t & 3;
  U8 wreg[4];
#pragma unroll
  for (int jj = 0; jj < 4; ++jj)
    wreg[jj].v = *(const bf16x8*)&pwb[(size_t)(oy * 256 + orow_c + 64 * jj) * C_ + oct_c * 8];

  for (int ks = 0; ks < 6; ++ks) {
    __syncthreads();  // Wa overwrite guard (also covers Xt on first iter)
#pragma unroll
    for (int jj = 0; jj < 4; ++jj) {
      const int orow = orow_c + 64 * jj;
      const int sw = (orow >> 1) & 3;
      *(bf16x8*)&Wa[orow][(oct_c ^ sw) * 8] = wreg[jj].v;
    }
    __syncthreads();
    if (ks < 5) {
#pragma unroll
      for (int jj = 0; jj < 4; ++jj)
        wreg[jj].v = *(const bf16x8*)&pwb[(size_t)(oy * 256 + orow_c + 64 * jj) * C_ +
                                          (ks + 1) * 32 + oct_c * 8];
    }
    bf16x8 bfrag[4];
#pragma unroll
    for (int ni = 0; ni < 4; ++ni)
      bfrag[ni] = *(const bf16x8*)&Xt[ni * 16 + fr][ks * 32 + fg * 8];
    __builtin_amdgcn_s_setprio(1);
#pragma unroll
    for (int mi = 0; mi < 4; ++mi) {
      const int ar = wid * 64 + mi * 16 + fr;
      bf16x8 a = *(const bf16x8*)&Wa[ar][(fg ^ ((ar >> 1) & 3)) * 8];
#pragma unroll
      for (int ni = 0; ni < 4; ++ni) acc[mi][ni] = MFMA(a, bfrag[ni], acc[mi][ni]);
    }
    __builtin_amdgcn_s_setprio(0);
  }
#pragma unroll
  for (int mi = 0; mi < 4; ++mi) {
    const int o4 = oy * 256 + wid * 64 + mi * 16 + fg * 4;
    const float b0 = pb[o4], b1 = pb[o4 + 1], b2 = pb[o4 + 2], b3 = pb[o4 + 3];
#pragma unroll
    for (int ni = 0; ni < 4; ++ni) {
      const int n = n0 + ni * 16 + fr;
      ushort4 pk;
      pk.x = f2bits(acc[mi][ni][0] + b0);
      pk.y = f2bits(acc[mi][ni][1] + b1);
      pk.z = f2bits(acc[mi][ni][2] + b2);
      pk.w = f2bits(acc[mi][ni][3] + b3);
      *(ushort4*)&y0t[((size_t)b * N_ + n) * A_ + o4] = pk;
    }
  }
}

// ============ K2: depthwise 3x3 + bias + residual; also writes skq = silu(y[:, :384])
__global__ __launch_bounds__(256) void k_dwc(const u16* __restrict__ y0t,
                                             const float* __restrict__ cw,
                                             const float* __restrict__ cb,
                                             u16* __restrict__ yt,
                                             u16* __restrict__ skq) {
  const int pid = blockIdx.x;
  const int L = (pid & 7) * 336 + (pid >> 3);  // 2688 = 8*336
  const int h = L % 56, at = (L / 56) % 3, b = L / 168;
  const int t = threadIdx.x;
  const int a = at * 256 + (t & 31) * 8;
  const int wl = t >> 5;
  float w9[9][8];
  float bias[8];
#pragma unroll
  for (int j = 0; j < 8; ++j) {
    bias[j] = cb[a + j];
#pragma unroll
    for (int k = 0; k < 9; ++k) w9[k][j] = cw[(a + j) * 9 + k];
  }
  const u16* src = y0t + (size_t)b * N_ * A_ + a;
  u16* dst = yt + (size_t)b * N_ * A_ + a;
  const bool hok0 = h > 0, hok2 = h < 55;
  for (int wc = 0; wc < 7; ++wc) {
    const int w = wc * 8 + wl;
    const bool wok0 = w > 0, wok2 = w < 55;
    U8 nb[9];
#pragma unroll
    for (int dh = -1; dh <= 1; ++dh) {
      const bool hok = (dh == -1) ? hok0 : ((dh == 1) ? hok2 : true);
#pragma unroll
      for (int dw = -1; dw <= 1; ++dw) {
        const int k = (dh + 1) * 3 + (dw + 1);
        const bool ok = hok && ((dw == -1) ? wok0 : ((dw == 1) ? wok2 : true));
        if (ok)
          nb[k].v = *(const bf16x8*)&src[(size_t)((h + dh) * 56 + (w + dw)) * A_];
        else
          nb[k].u[0] = nb[k].u[1] = nb[k].u[2] = nb[k].u[3] = 0u;
      }
    }
    U8 o;
    float sv[8];
#pragma unroll
    for (int j = 0; j < 8; ++j) {
      float s = bias[j] + bits2f(nb[4].s[j]);
#pragma unroll
      for (int k = 0; k < 9; ++k) s = fmaf(w9[k][j], bits2f(nb[k].s[j]), s);
      sv[j] = s;
      o.s[j] = f2bits(s);
    }
    *(bf16x8*)&dst[(size_t)(h * 56 + w) * A_] = o.v;
    if (a < 384) {
      U8 q;
#pragma unroll
      for (int j = 0; j < 8; ++j) q.s[j] = f2bits(silu_f(sv[j]));
      *(bf16x8*)&skq[((size_t)b * N_ + h * 56 + w) * 384 + a] = q.v;
    }
  }
}

// ============ K3: kfmean partials from skq k-part (pre-silu'd)
__global__ __launch_bounds__(256) void k_kfmean(const u16* __restrict__ skq,
                                                float* __restrict__ kfp) {
  const int ns = blockIdx.x, dc = blockIdx.y, b = blockIdx.z;
  const int t = threadIdx.x;
  const int dq = t & 15, nw = t >> 4;
  const u16* p = skq + ((size_t)b * N_ + ns * 448 + nw) * 384 + 192 + dc * 64 + dq * 4;
  float s0 = 0, s1 = 0, s2 = 0, s3 = 0;
#pragma unroll 4
  for (int i = 0; i < 28; ++i) {
    ushort4 u = *(const ushort4*)&p[(size_t)i * 16 * 384];
    s0 += bits2f(u.x);
    s1 += bits2f(u.y);
    s2 += bits2f(u.z);
    s3 += bits2f(u.w);
  }
  __shared__ float red[16][65];
  red[nw][dq * 4 + 0] = s0;
  red[nw][dq * 4 + 1] = s1;
  red[nw][dq * 4 + 2] = s2;
  red[nw][dq * 4 + 3] = s3;
  __syncthreads();
  if (t < 64) {
    float s = 0;
#pragma unroll
    for (int i = 0; i < 16; ++i) s += red[i][t];
    kfp[((size_t)ns * B_ + b) * Dq + dc * 64 + t] = s * (1.0f / (float)N_);
  }
}

// ============ K4: zinv[b][n] = 1/(sum_d kfm[d]*qf[n,d] + EPS)  (qf from skq)
__global__ __launch_bounds__(256) void k_z(const u16* __restrict__ skq,
                                           const float* __restrict__ kfp,
                                           float* __restrict__ zinv) {
  const int b = blockIdx.y;
  const int n = blockIdx.x * 256 + threadIdx.x;
  __shared__ float kf[192];
  if (threadIdx.x < 192) {
    float s = 0;
#pragma unroll
    for (int ns = 0; ns < 7; ++ns) s += kfp[((size_t)ns * B_ + b) * Dq + threadIdx.x];
    kf[threadIdx.x] = s;
  }
  __syncthreads();
  if (n < N_) {
    const u16* p = skq + ((size_t)b * N_ + n) * 384;
    float z = 0;
#pragma unroll
    for (int j = 0; j < 24; ++j) {
      U8 u;
      u.v = *(const bf16x8*)&p[j * 8];
#pragma unroll
      for (int i = 0; i < 8; ++i) z = fmaf(kf[j * 8 + i], bits2f(u.s[i]), z);
    }
    zinv[(size_t)b * N_ + n] = 1.0f / (z + EPSf);
  }
}

// ============ K5: vk GEMM, split-K over N (7 chunks), 128v x 192d tiles.
__global__ __launch_bounds__(256) void k_vk(const u16* __restrict__ skq,
                                            const u16* __restrict__ yt,
                                            float* __restrict__ vkpart) {
  const int pid = blockIdx.x;  // 336 = 8*42
  const int L = (pid & 7) * 42 + (pid >> 3);
  const int ns = L % 7;
  const int vblk = (L / 7) % 3;
  const int b = L / 21;
  const int t = threadIdx.x;
  const int lane = t & 63, wid = t >> 6;
  const int fr = lane & 15, fg = lane >> 4;
  const int vbase = (wid >> 1) * 64, dbase = (wid & 1) * 96;

  __shared__ u16 T[320 * 64];  // rows 0..191: K(d); rows 192..319: V
  unsigned* T32 = (unsigned*)T;

  const int oct0 = t & 7;
  const int pair = (t >> 3) & 31;
  const int nb0 = ns * 448;

  U8 pre[5][2];
  auto load_pre = [&](int n0) {
    const int n = nb0 + n0 + pair * 2;
#pragma unroll
    for (int j = 0; j < 5; ++j) {
      const int oct = oct0 + 8 * j;
      const u16* srcp;
      size_t stride;
      if (j < 3) {
        srcp = skq + ((size_t)b * N_ + n) * 384 + 192 + oct * 8;
        stride = 384;
      } else {
        srcp = yt + ((size_t)b * N_ + n) * A_ + 384 + vblk * 128 + (oct - 24) * 8;
        stride = A_;
      }
      pre[j][0].v = *(const bf16x8*)srcp;
      pre[j][1].v = *(const bf16x8*)(srcp + stride);
    }
  };

  f32x4 acc[4][6];
#pragma unroll
  for (int mi = 0; mi < 4; ++mi)
#pragma unroll
    for (int ni = 0; ni < 6; ++ni) acc[mi][ni] = (f32x4){0.f, 0.f, 0.f, 0.f};

  load_pre(0);
  for (int s = 0; s < 7; ++s) {
    __syncthreads();  // prior MFMA done reading T
#pragma unroll
    for (int j = 0; j < 5; ++j) {
      const int rowb = (oct0 + 8 * j) * 8;
#pragma unroll
      for (int i = 0; i < 8; ++i) {
        const int row = rowb + i;
        const int sw = (row & 7) ^ ((row >> 3) & 7);
        const unsigned val =
            ((unsigned)pre[j][0].s[i] & 0xffffu) | (((unsigned)pre[j][1].s[i]) << 16);
        T32[row * 32 + (pair ^ (sw << 2))] = val;
      }
    }
    __syncthreads();
    if (s < 6) load_pre((s + 1) * 64);  // prefetch next step under MFMA
    __builtin_amdgcn_s_setprio(1);
#pragma unroll
    for (int kf2 = 0; kf2 < 2; ++kf2) {
      bf16x8 bfrag[6];
#pragma unroll
      for (int ni = 0; ni < 6; ++ni) {
        const int row = dbase + ni * 16 + fr;
        const int sw = (row & 7) ^ ((row >> 3) & 7);
        bfrag[ni] = *(const bf16x8*)&T[row * 64 + ((kf2 * 32 + fg * 8) ^ (sw << 3))];
      }
#pragma unroll
      for (int mi = 0; mi < 4; ++mi) {
        const int row = 192 + vbase + mi * 16 + fr;
        const int sw = (row & 7) ^ ((row >> 3) & 7);
        bf16x8 a = *(const bf16x8*)&T[row * 64 + ((kf2 * 32 + fg * 8) ^ (sw << 3))];
#pragma unroll
        for (int ni = 0; ni < 6; ++ni) acc[mi][ni] = MFMA(a, bfrag[ni], acc[mi][ni]);
      }
    }
    __builtin_amdgcn_s_setprio(0);
  }
  float* base = vkpart + (((size_t)ns * 16 + b) * 3 + vblk) * (128 * 192);
#pragma unroll
  for (int mi = 0; mi < 4; ++mi)
#pragma unroll
    for (int ni = 0; ni < 6; ++ni) {
      const int v = vbase + mi * 16 + fg * 4;
      const int d = dbase + ni * 16 + fr;
      float* o = base + (size_t)v * 192 + d;
      o[0] = acc[mi][ni][0];
      o[192] = acc[mi][ni][1];
      o[384] = acc[mi][ni][2];
      o[576] = acc[mi][ni][3];
    }
}

// ============ K5b: reduce 7 partials -> vkb bf16 [b][384][192] (with 1/N)
__global__ __launch_bounds__(256) void k_vkred(const float* __restrict__ vkpart,
                                               u16* __restrict__ vkb) {
  const size_t e = ((size_t)blockIdx.x * 256 + threadIdx.x) * 8;
  constexpr size_t NSSTRIDE = (size_t)16 * 3 * 128 * 192;
  float4 s0 = {0, 0, 0, 0}, s1 = {0, 0, 0, 0};
#pragma unroll
  for (int ns = 0; ns < 7; ++ns) {
    float4 a0 = *(const float4*)&vkpart[ns * NSSTRIDE + e];
    float4 a1 = *(const float4*)&vkpart[ns * NSSTRIDE + e + 4];
    s0.x += a0.x; s0.y += a0.y; s0.z += a0.z; s0.w += a0.w;
    s1.x += a1.x; s1.y += a1.y; s1.z += a1.z; s1.w += a1.w;
  }
  const float sc = 1.0f / (float)N_;
  U8 r;
  r.s[0] = f2bits(s0.x * sc); r.s[1] = f2bits(s0.y * sc);
  r.s[2] = f2bits(s0.z * sc); r.s[3] = f2bits(s0.w * sc);
  r.s[4] = f2bits(s1.x * sc); r.s[5] = f2bits(s1.y * sc);
  r.s[6] = f2bits(s1.z * sc); r.s[7] = f2bits(s1.w * sc);
  *(bf16x8*)&vkb[e] = r.v;
}

// ============ K6: fused attn0 (vkb@qf /z) and gate (sigmoid(gwb@xs+gb)); attnt[n][v]
// Unified 10-iteration K-loop (2 attn0 + 8 gate), KSTEP=96, reg-prefetch staging.
__global__ __launch_bounds__(256) void k_gateattn(const u16* __restrict__ yt,
                                                  const u16* __restrict__ skq,
                                                  const float* __restrict__ zinv,
                                                  const u16* __restrict__ vkb,
                                                  const u16* __restrict__ gwb,
                                                  const float* __restrict__ gb,
                                                  u16* __restrict__ attnt) {
  const int pid = blockIdx.x;
  const int L = (pid & 7) * 196 + (pid >> 3);  // 1568 = 8*196
  const int vh = L & 1;
  const int n0 = ((L >> 1) % 49) * 64;
  const int b = L / 98;
  const int t = threadIdx.x;
  const int lane = t & 63, wid = t >> 6, wm = wid >> 1, wn = wid & 1;
  const int fr = lane & 15, fg = lane >> 4;
  __shared__ u16 Wa[192][104];  // 208B stride: 2-way bank alias (free)
  __shared__ u16 Xt[64][104];
  __shared__ float zl[64];
  if (t < 64) zl[t] = zinv[(size_t)b * N_ + n0 + t];
  const u16* yb = yt + ((size_t)b * N_ + n0) * A_;
  const u16* qb = skq + ((size_t)b * N_ + n0) * 384;
  const u16* wb0 = vkb + ((size_t)b * Vd + vh * 192) * 192;  // attn0 weights
  const u16* wb1 = gwb + (size_t)(vh * 192) * A_;            // gate weights

  // staging maps: W = 192 rows x 12 octets; X = 64 rows x 12 octets
  int wrow[9], woc[9];
#pragma unroll
  for (int j = 0; j < 9; ++j) { const int idx = j * 256 + t; wrow[j] = idx / 12; woc[j] = idx % 12; }
  int xrow[3], xoc[3];
#pragma unroll
  for (int j = 0; j < 3; ++j) { const int idx = j * 256 + t; xrow[j] = idx / 12; xoc[j] = idx % 12; }

  U8 wreg[9], xreg[3];
  auto loadW = [&](int ph, int ks0) {
#pragma unroll
    for (int j = 0; j < 9; ++j) {
      const u16* s = ph ? (wb1 + (size_t)wrow[j] * A_ + ks0 + woc[j] * 8)
                        : (wb0 + (size_t)wrow[j] * 192 + ks0 + woc[j] * 8);
      wreg[j].v = *(const bf16x8*)s;
    }
  };
  auto loadX = [&](int ph, int ks0) {
#pragma unroll
    for (int j = 0; j < 3; ++j) {
      const u16* s = ph ? (yb + (size_t)xrow[j] * A_ + ks0 + xoc[j] * 8)
                        : (qb + (size_t)xrow[j] * 384 + ks0 + xoc[j] * 8);
      xreg[j].v = *(const bf16x8*)s;
    }
  };

  f32x4 acc[6][2];
#pragma unroll
  for (int mi = 0; mi < 6; ++mi)
#pragma unroll
    for (int ni = 0; ni < 2; ++ni) acc[mi][ni] = (f32x4){0.f, 0.f, 0.f, 0.f};
  uint2 pp[6][2];

  loadW(0, 0);
  loadX(0, 0);
  for (int it = 0; it < 10; ++it) {
    __syncthreads();  // prior MFMA done reading LDS
#pragma unroll
    for (int j = 0; j < 9; ++j) *(bf16x8*)&Wa[wrow[j]][woc[j] * 8] = wreg[j].v;
#pragma unroll
    for (int j = 0; j < 3; ++j) *(bf16x8*)&Xt[xrow[j]][xoc[j] * 8] = xreg[j].v;
    __syncthreads();
    if (it < 9) {  // prefetch next iter under MFMA
      const int nit = it + 1;
      const int ph = nit >= 2;
      const int ks0 = ph ? (nit - 2) * 96 : nit * 96;
      loadW(ph, ks0);
      loadX(ph, ks0);
    }
    __builtin_amdgcn_s_setprio(1);
#pragma unroll
    for (int kf = 0; kf < 3; ++kf) {
      bf16x8 bfr[2];
#pragma unroll
      for (int ni = 0; ni < 2; ++ni)
        bfr[ni] = *(const bf16x8*)&Xt[wn * 32 + ni * 16 + fr][kf * 32 + fg * 8];
#pragma unroll
      for (int mi = 0; mi < 6; ++mi) {
        bf16x8 a = *(const bf16x8*)&Wa[wm * 96 + mi * 16 + fr][kf * 32 + fg * 8];
        acc[mi][0] = MFMA(a, bfr[0], acc[mi][0]);
        acc[mi][1] = MFMA(a, bfr[1], acc[mi][1]);
      }
    }
    __builtin_amdgcn_s_setprio(0);
    if (it == 1) {  // attn0 done: apply 1/z, stash packed, reset acc for gate
#pragma unroll
      for (int mi = 0; mi < 6; ++mi)
#pragma unroll
        for (int ni = 0; ni < 2; ++ni) {
          const float z = zl[wn * 32 + ni * 16 + fr];
          unsigned a0 = ((unsigned)f2bits(acc[mi][ni][0] * z) & 0xffffu) |
                        (((unsigned)f2bits(acc[mi][ni][1] * z) & 0xffffu) << 16);
          unsigned a1 = ((unsigned)f2bits(acc[mi][ni][2] * z) & 0xffffu) |
                        (((unsigned)f2bits(acc[mi][ni][3] * z) & 0xffffu) << 16);
          pp[mi][ni] = make_uint2(a0, a1);
          acc[mi][ni] = (f32x4){0.f, 0.f, 0.f, 0.f};
        }
    }
  }

  // ---- combine and write attnt[n][v]
#pragma unroll
  for (int mi = 0; mi < 6; ++mi) {
    const int vb = vh * 192 + wm * 96 + mi * 16 + fg * 4;
    const float g0 = gb[vb], g1 = gb[vb + 1], g2 = gb[vb + 2], g3 = gb[vb + 3];
#pragma unroll
    for (int ni = 0; ni < 2; ++ni) {
      const int n = n0 + wn * 32 + ni * 16 + fr;
      const uint2 p = pp[mi][ni];
      const float pv0 = bits2f((u16)(p.x & 0xffffu)), pv1 = bits2f((u16)(p.x >> 16));
      const float pv2 = bits2f((u16)(p.y & 0xffffu)), pv3 = bits2f((u16)(p.y >> 16));
      ushort4 o;
      o.x = f2bits(pv0 * sigm_f(acc[mi][ni][0] + g0));
      o.y = f2bits(pv1 * sigm_f(acc[mi][ni][1] + g1));
      o.z = f2bits(pv2 * sigm_f(acc[mi][ni][2] + g2));
      o.w = f2bits(pv3 * sigm_f(acc[mi][ni][3] + g3));
      *(ushort4*)&attnt[((size_t)b * N_ + n) * Vd + vb] = o;
    }
  }
}

// ============ K7: rms over v (384) per n, final combine (in place on attnt)
__global__ __launch_bounds__(256) void k_rmsfinal(const u16* __restrict__ yt,
                                                  const float* __restrict__ anw,
                                                  const float* __restrict__ svw,
                                                  u16* __restrict__ attnt) {
  const int b = blockIdx.y;
  const int n0 = blockIdx.x * 32;
  const int t = threadIdx.x;
  __shared__ float anws[384], svws[384];
  for (int i = t; i < 384; i += 256) {
    anws[i] = anw[i];
    svws[i] = svw[i];
  }
  __syncthreads();
  const int n = n0 + (t >> 3);
  const int vs = (t & 7) * 8;
  u16* ap = attnt + ((size_t)b * N_ + n) * Vd;
  U8 av[6];
  float ss = 0.f;
#pragma unroll
  for (int j = 0; j < 6; ++j) {
    av[j].v = *(const bf16x8*)&ap[vs + j * 64];
#pragma unroll
    for (int i = 0; i < 8; ++i) {
      const float f = bits2f(av[j].s[i]);
      ss = fmaf(f, f, ss);
    }
  }
  ss += __shfl_xor(ss, 1);
  ss += __shfl_xor(ss, 2);
  ss += __shfl_xor(ss, 4);
  const float rinv = rsqrtf(ss * (1.0f / (float)Vd) + EPSf);
  const u16* vp = yt + ((size_t)b * N_ + n) * A_ + 2 * Dq;
#pragma unroll
  for (int j = 0; j < 6; ++j) {
    U8 vv, o;
    vv.v = *(const bf16x8*)&vp[vs + j * 64];
#pragma unroll
    for (int i = 0; i < 8; ++i) {
      const int v = vs + j * 64 + i;
      const float val = bits2f(av[j].s[i]) * rinv * anws[v] + bits2f(vv.s[i]) * svws[v];
      o.s[i] = f2bits(val);
    }
    *(bf16x8*)&ap[vs + j * 64] = o.v;
  }
}

// ============ K8: out GEMM  out[b][c][n] = sum_v ow[c,v]*attnt[n][v] + ob[c]
// 192c x 64n per block, K=384 in 4 iters of 96, reg-prefetch staging.
__global__ __launch_bounds__(256) void k_out(const u16* __restrict__ attnt,
                                             const u16* __restrict__ owb,
                                             const float* __restrict__ ob,
                                             float* __restrict__ out) {
  const int n0 = blockIdx.x * 64;
  const int b = blockIdx.y;
  __shared__ u16 Wa[192][104];
  __shared__ u16 Xt[64][104];
  const int t = threadIdx.x;
  const int lane = t & 63, wid = t >> 6, wm = wid >> 1, wn = wid & 1;
  const int fr = lane & 15, fg = lane >> 4;
  const u16* xb = attnt + ((size_t)b * N_ + n0) * Vd;

  int wrow[9], woc[9];
#pragma unroll
  for (int j = 0; j < 9; ++j) { const int idx = j * 256 + t; wrow[j] = idx / 12; woc[j] = idx % 12; }
  int xrow[3], xoc[3];
#pragma unroll
  for (int j = 0; j < 3; ++j) { const int idx = j * 256 + t; xrow[j] = idx / 12; xoc[j] = idx % 12; }

  U8 wreg[9], xreg[3];
  auto loadW = [&](int ks0) {
#pragma unroll
    for (int j = 0; j < 9; ++j)
      wreg[j].v = *(const bf16x8*)&owb[(size_t)wrow[j] * Vd + ks0 + woc[j] * 8];
  };
  auto loadX = [&](int ks0) {
#pragma unroll
    for (int j = 0; j < 3; ++j)
      xreg[j].v = *(const bf16x8*)&xb[(size_t)xrow[j] * Vd + ks0 + xoc[j] * 8];
  };

  f32x4 acc[6][2];
#pragma unroll
  for (int mi = 0; mi < 6; ++mi)
#pragma unroll
    for (int ni = 0; ni < 2; ++ni) acc[mi][ni] = (f32x4){0.f, 0.f, 0.f, 0.f};

  loadW(0);
  loadX(0);
  for (int it = 0; it < 4; ++it) {
    __syncthreads();
#pragma unroll
    for (int j = 0; j < 9; ++j) *(bf16x8*)&Wa[wrow[j]][woc[j] * 8] = wreg[j].v;
#pragma unroll
    for (int j = 0; j < 3; ++j) *(bf16x8*)&Xt[xrow[j]][xoc[j] * 8] = xreg[j].v;
    __syncthreads();
    if (it < 3) {
      loadW((it + 1) * 96);
      loadX((it + 1) * 96);
    }
    __builtin_amdgcn_s_setprio(1);
#pragma unroll
    for (int kf = 0; kf < 3; ++kf) {
      bf16x8 bfr[2];
#pragma unroll
      for (int ni = 0; ni < 2; ++ni)
        bfr[ni] = *(const bf16x8*)&Xt[wn * 32 + ni * 16 + fr][kf * 32 + fg * 8];
#pragma unroll
      for (int mi = 0; mi < 6; ++mi) {
        bf16x8 a = *(const bf16x8*)&Wa[wm * 96 + mi * 16 + fr][kf * 32 + fg * 8];
        acc[mi][0] = MFMA(a, bfr[0], acc[mi][0]);
        acc[mi][1] = MFMA(a, bfr[1], acc[mi][1]);
      }
    }
    __builtin_amdgcn_s_setprio(0);
  }
#pragma unroll
  for (int mi = 0; mi < 6; ++mi) {
    const int c = wm * 96 + mi * 16 + fg * 4;
    const float b0 = ob[c], b1 = ob[c + 1], b2 = ob[c + 2], b3 = ob[c + 3];
#pragma unroll
    for (int ni = 0; ni < 2; ++ni) {
      const int n = n0 + wn * 32 + ni * 16 + fr;
      float* o = out + ((size_t)b * C_ + c) * N_ + n;
      o[0 * N_] = acc[mi][ni][0] + b0;
      o[1 * N_] = acc[mi][ni][1] + b1;
      o[2 * N_] = acc[mi][ni][2] + b2;
      o[3 * N_] = acc[mi][ni][3] + b3;
    }
  }
}

extern "C" void kernel_launch(void* const* d_in, const int* in_sizes, int n_in,
                              void* d_out, int out_size, void* d_ws, size_t ws_size,
                              hipStream_t stream) {
  (void)in_sizes; (void)n_in; (void)out_size; (void)ws_size;
  const float* x = (const float*)d_in[0];
  const float* pw = (const float*)d_in[1];
  const float* pb = (const float*)d_in[2];
  const float* cw = (const float*)d_in[3];
  const float* cb = (const float*)d_in[4];
  const float* gw = (const float*)d_in[5];
  const float* gb = (const float*)d_in[6];
  const float* anw = (const float*)d_in[7];
  const float* svw = (const float*)d_in[8];
  const float* ow = (const float*)d_in[9];
  const float* ob = (const float*)d_in[10];
  float* out = (float*)d_out;

  char* ws = (char*)d_ws;
  const size_t szY = (size_t)B_ * N_ * A_ * 2;  // 77,070,336
  u16* y0t = (u16*)(ws);
  u16* attnt = (u16*)(ws);                          // [B][N][384] bf16 (38,535,168)
  float* vkpart = (float*)(ws + 38535168);          // [7][16][3][128][192] f32 (33,030,144)
  u16* vkb = (u16*)(ws + 71565312);                 // [16][384][192] bf16 (2,359,296)
  u16* yt = (u16*)(ws + szY);                       // [B][N][A] bf16
  u16* skq = (u16*)(ws + 2 * szY);                  // [B][N][384] bf16 (38,535,168)
  char* ws2 = ws + 2 * szY + 38535168;
  float* kfp = (float*)(ws2);                       // [7][16][192] f32
  float* zinv = (float*)(ws2 + 86016);              // [B][N] f32
  u16* pwb = (u16*)(ws2 + 86016 + 200704);          // [768][192] bf16
  u16* gwb = (u16*)(ws2 + 86016 + 200704 + 294912); // [384][768] bf16
  u16* owb = (u16*)(ws2 + 86016 + 200704 + 294912 + 589824);  // [192][384] bf16

  k_prep<<<dim3(252), 256, 0, stream>>>(pw, gw, ow, pwb, gwb, owb);
  k_proj<<<dim3(49, 3, 16), 256, 0, stream>>>(x, pwb, pb, y0t);
  k_dwc<<<dim3(2688), 256, 0, stream>>>(y0t, cw, cb, yt, skq);
  k_kfmean<<<dim3(7, 3, 16), 256, 0, stream>>>(skq, kfp);
  k_z<<<dim3(13, 16), 256, 0, stream>>>(skq, kfp, zinv);
  k_vk<<<dim3(336), 256, 0, stream>>>(skq, yt, vkpart);
  k_vkred<<<dim3(576), 256, 0, stream>>>(vkpart, vkb);
  k_gateattn<<<dim3(1568), 256, 0, stream>>>(yt, skq, zinv, vkb, gwb, gb, attnt);
  k_rmsfinal<<<dim3(98, 16), 256, 0, stream>>>(yt, anw, svw, attnt);
  k_out<<<dim3(49, 16), 256, 0, stream>>>(attnt, owb, ob, out);
}